// Round 7
// baseline (524.425 us; speedup 1.0000x reference)
//
#include <hip/hip_runtime.h>
#include <hip/hip_bf16.h>
#include <cstdint>

constexpr int HIDDEN = 128, CTXD = 2048, HEADS = 4, NLAYERS = 3;
constexpr int KRBF = 720, KPAD = 736;  // 736 = 23 * 32
constexpr int KXH = 256;               // concat [x | h] K-dim

typedef __bf16 bf16x8 __attribute__((ext_vector_type(8)));
typedef float f32x4 __attribute__((ext_vector_type(4)));

static __device__ __forceinline__ unsigned short f2bf(float f) {
    union { float f; unsigned u; } v; v.f = f;
    unsigned r = v.u + 0x7fffu + ((v.u >> 16) & 1u);
    return (unsigned short)(r >> 16);
}
static __device__ __forceinline__ float bf2f(unsigned short s) {
    union { unsigned u; float f; } v; v.u = ((unsigned)s) << 16; return v.f;
}

// ---------------- weight transpose (f32 [B,R,C] -> bf16 [B,C,R]) ----------------
__global__ __launch_bounds__(256) void k_tr(const float* __restrict__ src,
                                            unsigned short* __restrict__ dst,
                                            int R, int C) {
    __shared__ unsigned short t[32][34];
    int b = blockIdx.z;
    int c0 = blockIdx.x * 32, r0 = blockIdx.y * 32;
    const float* s = src + (size_t)b * R * C;
    unsigned short* d = dst + (size_t)b * R * C;
    for (int rr = threadIdx.y; rr < 32; rr += 8) {
        int r = r0 + rr, c = c0 + threadIdx.x;
        unsigned short val = 0;
        if (r < R && c < C) val = f2bf(s[(size_t)r * C + c]);
        t[rr][threadIdx.x] = val;
    }
    __syncthreads();
    for (int rr = threadIdx.y; rr < 32; rr += 8) {
        int c = c0 + rr, r = r0 + threadIdx.x;
        if (c < C && r < R) d[(size_t)c * R + r] = t[threadIdx.x][rr];
    }
}

// ---------------- small elementwise prep kernels ----------------
__global__ __launch_bounds__(256) void k_w2bf(const float* __restrict__ W2,
                                              unsigned short* __restrict__ W2bf) {
    int i = blockIdx.x * 256 + threadIdx.x;
    if (i < 128 * CTXD) W2bf[i] = f2bf(W2[i]);
}
__global__ __launch_bounds__(256) void k_cpre(const float* __restrict__ ctx,
                                              const float* __restrict__ b2,
                                              unsigned short* __restrict__ cpre, int NG) {
    int i = blockIdx.x * 256 + threadIdx.x;
    if (i < NG * CTXD) cpre[i] = f2bf(ctx[i] + b2[i % CTXD]);
}
// Bc[l][o][0:128] = gatWt[l][o][0:128]  (Wx^T part)
__global__ __launch_bounds__(256) void k_bccopy(const unsigned short* __restrict__ gatWt,
                                                unsigned short* __restrict__ Bc) {
    int i = blockIdx.x * 256 + threadIdx.x;
    if (i >= NLAYERS * 512 * 128) return;
    int lo = i >> 7, k = i & 127;  // lo = l*512+o
    Bc[(size_t)lo * KXH + k] = gatWt[(size_t)lo * 2176 + k];
}

// ---------------- W1 transpose to bf16 [128][KPAD], zero-padded K ----------------
__global__ __launch_bounds__(256) void k_trW1(const float* __restrict__ W1,
                                              unsigned short* __restrict__ W1t) {
    int i = blockIdx.x * 256 + threadIdx.x;
    if (i >= 128 * KPAD) return;
    int c = i / KPAD, k = i % KPAD;
    unsigned short v = 0;
    if (k < KRBF) v = f2bf(W1[(size_t)k * 128 + c]);
    W1t[i] = v;
}

// ---------------- embedding gather ----------------
__global__ __launch_bounds__(256) void k_embed(const int* __restrict__ at,
                                               const float* __restrict__ W,
                                               const float* __restrict__ b,
                                               float* __restrict__ x,
                                               unsigned short* __restrict__ xh, int N) {
    int i = blockIdx.x * 256 + threadIdx.x;
    if (i >= N * HIDDEN) return;
    int n = i >> 7, c = i & 127;
    float v = W[(size_t)at[n] * HIDDEN + c] + b[c];
    x[i] = v;
    xh[(size_t)n * KXH + c] = f2bf(v);
}

// ---------------- fused RBF + Linear(720->128) via MFMA + BN + ReLU -> xh[:,128:256] ----------------
__global__ __launch_bounds__(256) void k_rbf_mfma(const float* __restrict__ pos,
                                                  const unsigned short* __restrict__ W1t,
                                                  const float* __restrict__ b1,
                                                  const float* __restrict__ g,
                                                  const float* __restrict__ bb,
                                                  const float* __restrict__ bm,
                                                  const float* __restrict__ bv,
                                                  unsigned short* __restrict__ xh, int N) {
    constexpr int LDT = 40;
    __shared__ unsigned short As[128 * LDT];
    __shared__ unsigned short Bs[128 * LDT];
    __shared__ float ps[128 * 3];
    const int tid = threadIdx.x;
    const int lane = tid & 63, wid = tid >> 6;
    const int nb = blockIdx.x * 128;
    for (int i = tid; i < 384; i += 256) {
        int n = nb + i / 3;
        ps[i] = (n < N) ? pos[(size_t)n * 3 + (i % 3)] : 1.0e9f;  // pad rows -> rbf = 0
    }
    __syncthreads();
    const int sr = tid >> 1, sk = (tid & 1) * 16;
    const int wr = (wid >> 1) * 64, wc = (wid & 1) * 64;
    const int fr = lane & 15, kg = lane >> 4;
    f32x4 acc[4][4];
#pragma unroll
    for (int i = 0; i < 4; i++)
#pragma unroll
        for (int j = 0; j < 4; j++)
#pragma unroll
            for (int r = 0; r < 4; r++) acc[i][j][r] = 0.f;
    const float p0 = ps[sr * 3], p1 = ps[sr * 3 + 1], p2 = ps[sr * 3 + 2];
    const unsigned short* bp = W1t + (size_t)sr * KPAD + sk;
    uint4 bv0 = *(const uint4*)bp, bv1 = *(const uint4*)(bp + 8);
    constexpr int NST = KPAD / 32;
    for (int ks = 0; ks < NST; ++ks) {
        unsigned short av[16];
#pragma unroll
        for (int j = 0; j < 16; j++) {
            int kglob = ks * 32 + sk + j;
            float v = 0.f;
            if (kglob < KRBF) {
                int d = kglob / 240, bin = kglob % 240;
                float mu = -30.f + (60.f / 239.f) * (float)bin;
                float p = (d == 0) ? p0 : ((d == 1) ? p1 : p2);
                float df = p - mu;
                v = __expf(-0.5f * df * df);
            }
            av[j] = f2bf(v);
        }
        __syncthreads();
        *(uint4*)&As[sr * LDT + sk] = *(const uint4*)&av[0];
        *(uint4*)&As[sr * LDT + sk + 8] = *(const uint4*)&av[8];
        *(uint4*)&Bs[sr * LDT + sk] = bv0;
        *(uint4*)&Bs[sr * LDT + sk + 8] = bv1;
        __syncthreads();
        if (ks + 1 < NST) {
            const unsigned short* bp2 = W1t + (size_t)sr * KPAD + (ks + 1) * 32 + sk;
            bv0 = *(const uint4*)bp2;
            bv1 = *(const uint4*)(bp2 + 8);
        }
        bf16x8 afr[4], bfr[4];
#pragma unroll
        for (int i = 0; i < 4; i++) {
            afr[i] = *reinterpret_cast<const bf16x8*>(&As[(wr + i * 16 + fr) * LDT + kg * 8]);
            bfr[i] = *reinterpret_cast<const bf16x8*>(&Bs[(wc + i * 16 + fr) * LDT + kg * 8]);
        }
#pragma unroll
        for (int i = 0; i < 4; i++)
#pragma unroll
            for (int j = 0; j < 4; j++)
                acc[i][j] = __builtin_amdgcn_mfma_f32_16x16x32_bf16(afr[i], bfr[j], acc[i][j], 0, 0, 0);
    }
    const int rg = lane >> 4;
#pragma unroll
    for (int i = 0; i < 4; i++) {
#pragma unroll
        for (int j = 0; j < 4; j++) {
            int col = wc + j * 16 + fr;
            float sc = g[col] * rsqrtf(bv[col] + 1e-5f);
            float sh = bb[col] - bm[col] * sc;
            float bc = b1[col];
#pragma unroll
            for (int r = 0; r < 4; r++) {
                int row = nb + wr + i * 16 + rg * 4 + r;
                if (row < N) {
                    float y = (acc[i][j][r] + bc) * sc + sh;
                    y = fmaxf(y, 0.f);
                    xh[(size_t)row * KXH + 128 + col] = f2bf(y);
                }
            }
        }
    }
}

// ---------------- shared MFMA GEMM core: C[M,N] = A[M,K] @ Bt[N,K]^T ----------------
// MODE 0: bf16 out. MODE 2: f32 out. MODE 3: bf16 out + cw[batch[row]*512+col].
template <int MODE>
__device__ __forceinline__ void gemm_core(unsigned short* As, unsigned short* Bs,
                                          const unsigned short* __restrict__ A, int lda, int M,
                                          const unsigned short* __restrict__ Bt, int ldb, int K,
                                          void* __restrict__ Cout, int ldc,
                                          const int* __restrict__ batch,
                                          const float* __restrict__ cw,
                                          int m0, int n0) {
    constexpr int LDT = 40;
    const int tid = threadIdx.x;
    const int lane = tid & 63, wid = tid >> 6;
    const int wr = (wid >> 1) * 64, wc = (wid & 1) * 64;
    const int sr = tid >> 1, sk = (tid & 1) * 16;
    f32x4 acc[4][4];
#pragma unroll
    for (int i = 0; i < 4; i++)
#pragma unroll
        for (int j = 0; j < 4; j++)
#pragma unroll
            for (int r = 0; r < 4; r++) acc[i][j][r] = 0.f;
    const int nst = K / 32;
    const int arow = min(m0 + sr, M - 1);
    const unsigned short* ap = A + (size_t)arow * lda + sk;
    const unsigned short* bp = Bt + (size_t)(n0 + sr) * ldb + sk;
    uint4 av0 = *(const uint4*)ap, av1 = *(const uint4*)(ap + 8);
    uint4 bv0 = *(const uint4*)bp, bv1 = *(const uint4*)(bp + 8);
    const int fr = lane & 15, kg = lane >> 4;
    for (int ks = 0; ks < nst; ++ks) {
        __syncthreads();
        *(uint4*)&As[sr * LDT + sk] = av0;
        *(uint4*)&As[sr * LDT + sk + 8] = av1;
        *(uint4*)&Bs[sr * LDT + sk] = bv0;
        *(uint4*)&Bs[sr * LDT + sk + 8] = bv1;
        __syncthreads();
        if (ks + 1 < nst) {  // prefetch next K-step into regs, overlaps with MFMA below
            const unsigned short* ap2 = A + (size_t)arow * lda + (ks + 1) * 32 + sk;
            const unsigned short* bp2 = Bt + (size_t)(n0 + sr) * ldb + (ks + 1) * 32 + sk;
            av0 = *(const uint4*)ap2; av1 = *(const uint4*)(ap2 + 8);
            bv0 = *(const uint4*)bp2; bv1 = *(const uint4*)(bp2 + 8);
        }
        bf16x8 afr[4], bfr[4];
#pragma unroll
        for (int i = 0; i < 4; i++) {
            afr[i] = *reinterpret_cast<const bf16x8*>(&As[(wr + i * 16 + fr) * LDT + kg * 8]);
            bfr[i] = *reinterpret_cast<const bf16x8*>(&Bs[(wc + i * 16 + fr) * LDT + kg * 8]);
        }
#pragma unroll
        for (int i = 0; i < 4; i++)
#pragma unroll
            for (int j = 0; j < 4; j++)
                acc[i][j] = __builtin_amdgcn_mfma_f32_16x16x32_bf16(afr[i], bfr[j], acc[i][j], 0, 0, 0);
    }
    const int rg = lane >> 4;  // C/D: col = lane&15, row = (lane>>4)*4 + reg
#pragma unroll
    for (int i = 0; i < 4; i++) {
#pragma unroll
        for (int j = 0; j < 4; j++) {
            int col = n0 + wc + j * 16 + fr;
#pragma unroll
            for (int r = 0; r < 4; r++) {
                int row = m0 + wr + i * 16 + rg * 4 + r;
                if (row < M) {
                    float vv = acc[i][j][r];
                    if (MODE == 2) {
                        ((float*)Cout)[(size_t)row * ldc + col] = vv;
                    } else if (MODE == 3) {
                        vv += cw[(size_t)batch[row] * 512 + col];
                        ((unsigned short*)Cout)[(size_t)row * ldc + col] = f2bf(vv);
                    } else {
                        ((unsigned short*)Cout)[(size_t)row * ldc + col] = f2bf(vv);
                    }
                }
            }
        }
    }
}

// GAT per-layer node GEMM (MODE 3)
__global__ __launch_bounds__(256) void k_gemm3(const unsigned short* __restrict__ A, int M,
                                               const unsigned short* __restrict__ Bt,
                                               unsigned short* __restrict__ C,
                                               const int* __restrict__ batch,
                                               const float* __restrict__ cw) {
    constexpr int LDT = 40;
    __shared__ unsigned short As[128 * LDT];
    __shared__ unsigned short Bs[128 * LDT];
    gemm_core<3>(As, Bs, A, KXH, M, Bt, KXH, KXH, C, 512, batch, cw,
                 blockIdx.x * 128, blockIdx.y * 128);
}

// merged weight-prep GEMMs: z<3 -> Bc[l][:,128:256] = Wc[l]^T @ W2^T; z>=3 -> cW[l] = cpre @ Wc[l]
__global__ __launch_bounds__(256) void k_prep(const unsigned short* __restrict__ gatWt,
                                              const unsigned short* __restrict__ W2bf,
                                              const unsigned short* __restrict__ cpre,
                                              unsigned short* __restrict__ Bc,
                                              float* __restrict__ cW, int NG) {
    constexpr int LDT = 40;
    __shared__ unsigned short As[128 * LDT];
    __shared__ unsigned short Bs[128 * LDT];
    int z = blockIdx.z;
    if (z < 3) {
        if (blockIdx.y != 0) return;
        gemm_core<0>(As, Bs, gatWt + (size_t)z * 512 * 2176 + 128, 2176, 512,
                     W2bf, CTXD, CTXD, Bc + (size_t)z * 512 * KXH + 128, KXH,
                     nullptr, nullptr, blockIdx.x * 128, 0);
    } else {
        if (blockIdx.x != 0) return;
        int zz = z - 3;
        gemm_core<2>(As, Bs, cpre, CTXD, NG, gatWt + (size_t)zz * 512 * 2176 + 128, 2176, CTXD,
                     cW + (size_t)zz * NG * 512, 512, nullptr, nullptr, 0, blockIdx.y * 128);
    }
}

// ---------------- attention logits: a_src/a_dst [N,4] ----------------
__global__ __launch_bounds__(256) void k_att(const unsigned short* __restrict__ xs,
                                             const float* __restrict__ att_s,
                                             const float* __restrict__ att_d,
                                             float* __restrict__ a_src,
                                             float* __restrict__ a_dst, int N) {
    int tid = threadIdx.x, lane = tid & 63, wid = tid >> 6;
    int n = blockIdx.x * 4 + wid;
    if (n >= N) return;
    int h = lane >> 4, c0 = (lane & 15) * 8;
    uint4 raw = *(const uint4*)(xs + (size_t)n * 512 + h * 128 + c0);
    const unsigned short* rs = (const unsigned short*)&raw;
    float ss = 0.f, sd = 0.f;
#pragma unroll
    for (int j = 0; j < 8; j++) {
        float xv = bf2f(rs[j]);
        ss += xv * att_s[h * 128 + c0 + j];
        sd += xv * att_d[h * 128 + c0 + j];
    }
#pragma unroll
    for (int d = 1; d < 16; d <<= 1) {
        ss += __shfl_xor(ss, d);
        sd += __shfl_xor(sd, d);
    }
    if ((lane & 15) == 0) {
        a_src[n * 4 + h] = ss;
        a_dst[n * 4 + h] = sd;
    }
}

// ---------------- CSR build ----------------
__global__ void k_cnt_init(int* cnt, int N) {
    int i = blockIdx.x * 256 + threadIdx.x;
    if (i < N) cnt[i] = 1;  // self-loop
}
__global__ void k_cnt(const int* __restrict__ ei, int E, int* cnt) {
    int i = blockIdx.x * 256 + threadIdx.x;
    if (i < E) atomicAdd(&cnt[ei[E + i]], 1);
}
__global__ __launch_bounds__(1024) void k_scan(const int* __restrict__ cnt, int* __restrict__ rowptr,
                                               int* __restrict__ cursor, int n) {
    __shared__ int wsum[16];
    __shared__ int carry;
    int tid = threadIdx.x, lane = tid & 63, wid = tid >> 6;
    if (tid == 0) carry = 0;
    __syncthreads();
    for (int basei = 0; basei < n; basei += 1024) {
        int i = basei + tid;
        int v = (i < n) ? cnt[i] : 0;
        int s = v;
#pragma unroll
        for (int d = 1; d < 64; d <<= 1) {
            int t = __shfl_up(s, (unsigned)d);
            if (lane >= d) s += t;
        }
        if (lane == 63) wsum[wid] = s;
        __syncthreads();
        if (wid == 0 && lane < 16) {
            int ws = wsum[lane]; int t = ws;
#pragma unroll
            for (int d = 1; d < 16; d <<= 1) {
                int u = __shfl_up(t, (unsigned)d);
                if (lane >= d) t += u;
            }
            wsum[lane] = t - ws;  // exclusive wave offsets
        }
        __syncthreads();
        int excl = carry + wsum[wid] + (s - v);
        if (i < n) { rowptr[i] = excl; cursor[i] = excl; }
        __syncthreads();
        if (tid == 1023) carry += wsum[15] + s;
        __syncthreads();
    }
    if (tid == 0) rowptr[n] = carry;
}
__global__ void k_fill(const int* __restrict__ ei, int E, int N, int* cursor,
                       int* csrc, int* cdst) {
    int i = blockIdx.x * 256 + threadIdx.x;
    if (i >= E + N) return;
    int s, d;
    if (i < E) { s = ei[i]; d = ei[E + i]; }
    else { s = i - E; d = s; }
    int slot = atomicAdd(&cursor[d], 1);
    csrc[slot] = s;
    cdst[slot] = d;
}

// ---------------- per-edge leaky logits ----------------
__global__ __launch_bounds__(256) void k_alpha(const int* __restrict__ csrc,
                                               const int* __restrict__ cdst,
                                               const float* __restrict__ a_src,
                                               const float* __restrict__ a_dst,
                                               float* __restrict__ alpha, int M) {
    int i = blockIdx.x * 256 + threadIdx.x;
    if (i >= M) return;
    int s = csrc[i], d = cdst[i];
    float4 as = *(const float4*)(a_src + (size_t)s * 4);
    float4 ad = *(const float4*)(a_dst + (size_t)d * 4);
    float4 o;
    o.x = as.x + ad.x; o.x = o.x > 0.f ? o.x : 0.2f * o.x;
    o.y = as.y + ad.y; o.y = o.y > 0.f ? o.y : 0.2f * o.y;
    o.z = as.z + ad.z; o.z = o.z > 0.f ? o.z : 0.2f * o.z;
    o.w = as.w + ad.w; o.w = o.w > 0.f ? o.w : 0.2f * o.w;
    *(float4*)(alpha + (size_t)i * 4) = o;
}

// ---------------- per-node softmax over incoming edges (alpha -> weights, in place) ---------
__global__ __launch_bounds__(256) void k_soft(const int* __restrict__ rowptr,
                                              float* __restrict__ alpha, int N) {
    int n = blockIdx.x * 256 + threadIdx.x;
    if (n >= N) return;
    int beg = rowptr[n], end = rowptr[n + 1];
    float m0 = -1e30f, m1 = -1e30f, m2 = -1e30f, m3 = -1e30f;
    for (int e = beg; e < end; e++) {
        float4 a = *(const float4*)(alpha + (size_t)e * 4);
        m0 = fmaxf(m0, a.x); m1 = fmaxf(m1, a.y);
        m2 = fmaxf(m2, a.z); m3 = fmaxf(m3, a.w);
    }
    float s0 = 0.f, s1 = 0.f, s2 = 0.f, s3 = 0.f;
    for (int e = beg; e < end; e++) {
        float4 a = *(const float4*)(alpha + (size_t)e * 4);
        s0 += __expf(a.x - m0); s1 += __expf(a.y - m1);
        s2 += __expf(a.z - m2); s3 += __expf(a.w - m3);
    }
    float i0 = 1.f / fmaxf(s0, 1e-16f), i1 = 1.f / fmaxf(s1, 1e-16f);
    float i2 = 1.f / fmaxf(s2, 1e-16f), i3 = 1.f / fmaxf(s3, 1e-16f);
    for (int e = beg; e < end; e++) {
        float4 a = *(const float4*)(alpha + (size_t)e * 4);
        float4 w;
        w.x = __expf(a.x - m0) * i0; w.y = __expf(a.y - m1) * i1;
        w.z = __expf(a.z - m2) * i2; w.w = __expf(a.w - m3) * i3;
        *(float4*)(alpha + (size_t)e * 4) = w;
    }
}

// ---------------- weighted gather + head-mean + BN + GELU + residual ----------------
__global__ __launch_bounds__(256) void k_gather(const int* __restrict__ rowptr,
                                                const int* __restrict__ csrc,
                                                const float* __restrict__ alpha,
                                                const unsigned short* __restrict__ xs,
                                                const float* __restrict__ gbias,
                                                const float* __restrict__ bg,
                                                const float* __restrict__ bb,
                                                const float* __restrict__ bm,
                                                const float* __restrict__ bv,
                                                float* __restrict__ x,
                                                unsigned short* __restrict__ xh, int N) {
    int tid = threadIdx.x, lane = tid & 63, wid = tid >> 6;
    int n = blockIdx.x * 4 + wid;
    if (n >= N) return;
    int beg = rowptr[n], end = rowptr[n + 1];
    const int h = lane >> 4, c0i = (lane & 15) * 8;
    float acc[8];
#pragma unroll
    for (int j = 0; j < 8; j++) acc[j] = 0.f;
    int e = beg;
    for (; e + 4 <= end; e += 4) {
        int s0 = csrc[e], s1 = csrc[e + 1], s2 = csrc[e + 2], s3 = csrc[e + 3];
        float w0 = alpha[(size_t)e * 4 + h];
        float w1 = alpha[(size_t)(e + 1) * 4 + h];
        float w2 = alpha[(size_t)(e + 2) * 4 + h];
        float w3 = alpha[(size_t)(e + 3) * 4 + h];
        uint4 r0 = *(const uint4*)(xs + ((size_t)s0 << 9) + (h << 7) + c0i);
        uint4 r1 = *(const uint4*)(xs + ((size_t)s1 << 9) + (h << 7) + c0i);
        uint4 r2 = *(const uint4*)(xs + ((size_t)s2 << 9) + (h << 7) + c0i);
        uint4 r3 = *(const uint4*)(xs + ((size_t)s3 << 9) + (h << 7) + c0i);
        const unsigned short* q0 = (const unsigned short*)&r0;
        const unsigned short* q1 = (const unsigned short*)&r1;
        const unsigned short* q2 = (const unsigned short*)&r2;
        const unsigned short* q3 = (const unsigned short*)&r3;
#pragma unroll
        for (int j = 0; j < 8; j++) acc[j] += w0 * bf2f(q0[j]);
#pragma unroll
        for (int j = 0; j < 8; j++) acc[j] += w1 * bf2f(q1[j]);
#pragma unroll
        for (int j = 0; j < 8; j++) acc[j] += w2 * bf2f(q2[j]);
#pragma unroll
        for (int j = 0; j < 8; j++) acc[j] += w3 * bf2f(q3[j]);
    }
    for (; e < end; e++) {
        int s0 = csrc[e];
        float w0 = alpha[(size_t)e * 4 + h];
        uint4 r0 = *(const uint4*)(xs + ((size_t)s0 << 9) + (h << 7) + c0i);
        const unsigned short* q0 = (const unsigned short*)&r0;
#pragma unroll
        for (int j = 0; j < 8; j++) acc[j] += w0 * bf2f(q0[j]);
    }
    // head mean across lanes (h = lane>>4)
#pragma unroll
    for (int j = 0; j < 8; j++) {
        acc[j] += __shfl_xor(acc[j], 16);
        acc[j] += __shfl_xor(acc[j], 32);
    }
    if (lane < 16) {
#pragma unroll
        for (int j = 0; j < 8; j++) {
            int c = c0i + j;
            float t = acc[j] * 0.25f + gbias[c];
            float sc = bg[c] * rsqrtf(bv[c] + 1e-5f);
            float y = (t - bm[c]) * sc + bb[c];
            float ge = 0.5f * y * (1.f + erff(y * 0.70710678118f));
            float xn = x[(size_t)n * 128 + c] + ge;
            x[(size_t)n * 128 + c] = xn;
            xh[(size_t)n * KXH + c] = f2bf(xn);
        }
    }
}

// ---------------- fused pool + final linear ----------------
__global__ __launch_bounds__(256) void k_pool(const float* __restrict__ x,
                                              const int* __restrict__ batch,
                                              const float* __restrict__ W,
                                              const float* __restrict__ bo,
                                              float* __restrict__ out, int N) {
    __shared__ float xg[128];
    __shared__ float tmp[256];
    __shared__ int bounds[2];
    int g = blockIdx.x, tid = threadIdx.x;
    if (tid < 2) {
        int key = g + tid, lo = 0, hi = N;
        while (lo < hi) { int mid = (lo + hi) >> 1; if (batch[mid] < key) lo = mid + 1; else hi = mid; }
        bounds[tid] = lo;
    }
    __syncthreads();
    int s = bounds[0], e = bounds[1];
    int c = tid & 127, rgp = tid >> 7;
    float a = 0.f;
    for (int n = s + rgp; n < e; n += 2) a += x[(size_t)n * 128 + c];
    tmp[tid] = a;
    __syncthreads();
    if (tid < 128) xg[tid] = tmp[tid] + tmp[tid + 128];
    __syncthreads();
    float cntf = (float)(e - s);
    for (int j = tid; j < 1024; j += 256) {
        float o = cntf * bo[j];
        for (int cc = 0; cc < 128; cc++) o += xg[cc] * W[(size_t)cc * 1024 + j];
        out[(size_t)g * 1024 + j] = o;
    }
}

extern "C" void kernel_launch(void* const* d_in, const int* in_sizes, int n_in,
                              void* d_out, int out_size, void* d_ws, size_t ws_size,
                              hipStream_t stream) {
    const int N = in_sizes[0];
    const int E = in_sizes[2] / 2;
    const int NG = in_sizes[5] / CTXD;
    const int* at = (const int*)d_in[0];
    const float* pos = (const float*)d_in[1];
    const int* ei = (const int*)d_in[2];
    const int* batch = (const int*)d_in[4];
    const float* ctx = (const float*)d_in[5];
    const float* embW = (const float*)d_in[6];
    const float* embB = (const float*)d_in[7];
    const float* W1 = (const float*)d_in[8];
    const float* b1 = (const float*)d_in[9];
    const float* rg = (const float*)d_in[10];
    const float* rb = (const float*)d_in[11];
    const float* rm = (const float*)d_in[12];
    const float* rv = (const float*)d_in[13];
    const float* W2 = (const float*)d_in[14];
    const float* b2 = (const float*)d_in[15];
    const float* gatW = (const float*)d_in[16];
    const float* atts = (const float*)d_in[17];
    const float* attd = (const float*)d_in[18];
    const float* gbias = (const float*)d_in[19];
    const float* bg = (const float*)d_in[20];
    const float* bbb = (const float*)d_in[21];
    const float* bm = (const float*)d_in[22];
    const float* bv = (const float*)d_in[23];
    const float* outW = (const float*)d_in[24];
    const float* outb = (const float*)d_in[25];
    float* out = (float*)d_out;

    char* basep = (char*)d_ws;
    size_t off = 0;
    auto alloc = [&](size_t bytes) -> char* {
        char* p = basep + off;
        off = (off + bytes + 255) & ~(size_t)255;
        return p;
    };
    unsigned short* xh = (unsigned short*)alloc((size_t)N * KXH * 2);
    float* x = (float*)alloc((size_t)N * 128 * 4);
    unsigned short* xs = (unsigned short*)alloc((size_t)N * 512 * 2);
    float* a_src = (float*)alloc((size_t)N * 4 * 4);
    float* a_dst = (float*)alloc((size_t)N * 4 * 4);
    int* cnt = (int*)alloc((size_t)N * 4);
    int* rowptr = (int*)alloc((size_t)(N + 1) * 4);
    int* cursor = (int*)alloc((size_t)N * 4);
    int* csrc = (int*)alloc((size_t)(E + N) * 4);
    int* cdst = (int*)alloc((size_t)(E + N) * 4);
    float* alpha = (float*)alloc((size_t)(E + N) * 4 * 4);
    unsigned short* gatWt = (unsigned short*)alloc((size_t)NLAYERS * 512 * 2176 * 2);
    unsigned short* W1t = (unsigned short*)alloc((size_t)128 * KPAD * 2);
    unsigned short* W2bf = (unsigned short*)alloc((size_t)128 * CTXD * 2);
    unsigned short* cpre = (unsigned short*)alloc((size_t)NG * CTXD * 2);
    unsigned short* Bc = (unsigned short*)alloc((size_t)NLAYERS * 512 * KXH * 2);
    float* cW = (float*)alloc((size_t)NLAYERS * NG * 512 * 4);
    (void)ws_size; (void)n_in; (void)out_size;

    // ---- weight prep ----
    {
        dim3 b(32, 8);
        dim3 g1((512 + 31) / 32, (2176 + 31) / 32, NLAYERS);
        k_tr<<<g1, b, 0, stream>>>(gatW, gatWt, 2176, 512);
        k_trW1<<<(128 * KPAD + 255) / 256, 256, 0, stream>>>(W1, W1t);
        k_w2bf<<<(128 * CTXD + 255) / 256, 256, 0, stream>>>(W2, W2bf);
        k_cpre<<<(NG * CTXD + 255) / 256, 256, 0, stream>>>(ctx, b2, cpre, NG);
        k_bccopy<<<(NLAYERS * 512 * 128 + 255) / 256, 256, 0, stream>>>(gatWt, Bc);
        dim3 gp(4, 4, 6);
        k_prep<<<gp, 256, 0, stream>>>(gatWt, W2bf, cpre, Bc, cW, NG);
    }
    // ---- node features ----
    k_embed<<<(N * 128 + 255) / 256, 256, 0, stream>>>(at, embW, embB, x, xh, N);
    k_rbf_mfma<<<(N + 127) / 128, 256, 0, stream>>>(pos, W1t, b1, rg, rb, rm, rv, xh, N);
    // ---- CSR (dst-sorted incoming edges incl. self-loops) ----
    k_cnt_init<<<(N + 255) / 256, 256, 0, stream>>>(cnt, N);
    k_cnt<<<(E + 255) / 256, 256, 0, stream>>>(ei, E, cnt);
    k_scan<<<1, 1024, 0, stream>>>(cnt, rowptr, cursor, N);
    k_fill<<<(E + N + 255) / 256, 256, 0, stream>>>(ei, E, N, cursor, csrc, cdst);
    // ---- GAT layers ----
    {
        dim3 g((N + 127) / 128, 4, 1);
        const int M = E + N;
        for (int l = 0; l < NLAYERS; l++) {
            k_gemm3<<<g, 256, 0, stream>>>(xh, N, Bc + (size_t)l * 512 * KXH,
                                           xs, batch, cW + (size_t)l * NG * 512);
            k_att<<<(N + 3) / 4, 256, 0, stream>>>(xs, atts + l * HEADS * 128, attd + l * HEADS * 128,
                                                   a_src, a_dst, N);
            k_alpha<<<(M + 255) / 256, 256, 0, stream>>>(csrc, cdst, a_src, a_dst, alpha, M);
            k_soft<<<(N + 255) / 256, 256, 0, stream>>>(rowptr, alpha, N);
            k_gather<<<(N + 3) / 4, 256, 0, stream>>>(rowptr, csrc, alpha, xs,
                                                      gbias + l * 128, bg + l * 128, bbb + l * 128,
                                                      bm + l * 128, bv + l * 128, x, xh, N);
        }
    }
    k_pool<<<NG, 256, 0, stream>>>(x, batch, outW, outb, out, N);
}

// Round 8
// 474.706 us; speedup vs baseline: 1.1047x; 1.1047x over previous
//
#include <hip/hip_runtime.h>
#include <hip/hip_bf16.h>
#include <cstdint>

constexpr int HIDDEN = 128, CTXD = 2048, HEADS = 4, NLAYERS = 3;
constexpr int KRBF = 720, KPAD = 736;  // 736 = 23 * 32
constexpr int KXH = 256;               // concat [x | h] K-dim

typedef __bf16 bf16x8 __attribute__((ext_vector_type(8)));
typedef float f32x4 __attribute__((ext_vector_type(4)));

static __device__ __forceinline__ unsigned short f2bf(float f) {
    union { float f; unsigned u; } v; v.f = f;
    unsigned r = v.u + 0x7fffu + ((v.u >> 16) & 1u);
    return (unsigned short)(r >> 16);
}
static __device__ __forceinline__ float bf2f(unsigned short s) {
    union { unsigned u; float f; } v; v.u = ((unsigned)s) << 16; return v.f;
}

// ---------------- weight transpose (f32 [B,R,C] -> bf16 [B,C,R]) ----------------
__global__ __launch_bounds__(256) void k_tr(const float* __restrict__ src,
                                            unsigned short* __restrict__ dst,
                                            int R, int C) {
    __shared__ unsigned short t[32][34];
    int b = blockIdx.z;
    int c0 = blockIdx.x * 32, r0 = blockIdx.y * 32;
    const float* s = src + (size_t)b * R * C;
    unsigned short* d = dst + (size_t)b * R * C;
    for (int rr = threadIdx.y; rr < 32; rr += 8) {
        int r = r0 + rr, c = c0 + threadIdx.x;
        unsigned short val = 0;
        if (r < R && c < C) val = f2bf(s[(size_t)r * C + c]);
        t[rr][threadIdx.x] = val;
    }
    __syncthreads();
    for (int rr = threadIdx.y; rr < 32; rr += 8) {
        int c = c0 + rr, r = r0 + threadIdx.x;
        if (c < C && r < R) d[(size_t)c * R + r] = t[threadIdx.x][rr];
    }
}

// ---------------- small elementwise prep kernels ----------------
__global__ __launch_bounds__(256) void k_w2bf(const float* __restrict__ W2,
                                              unsigned short* __restrict__ W2bf) {
    int i = blockIdx.x * 256 + threadIdx.x;
    if (i < 128 * CTXD) W2bf[i] = f2bf(W2[i]);
}
__global__ __launch_bounds__(256) void k_cpre(const float* __restrict__ ctx,
                                              const float* __restrict__ b2,
                                              unsigned short* __restrict__ cpre, int NG) {
    int i = blockIdx.x * 256 + threadIdx.x;
    if (i < NG * CTXD) cpre[i] = f2bf(ctx[i] + b2[i % CTXD]);
}
// Bc[l][o][0:128] = gatWt[l][o][0:128]  (Wx^T part)
__global__ __launch_bounds__(256) void k_bccopy(const unsigned short* __restrict__ gatWt,
                                                unsigned short* __restrict__ Bc) {
    int i = blockIdx.x * 256 + threadIdx.x;
    if (i >= NLAYERS * 512 * 128) return;
    int lo = i >> 7, k = i & 127;  // lo = l*512+o
    Bc[(size_t)lo * KXH + k] = gatWt[(size_t)lo * 2176 + k];
}

// ---------------- W1 transpose to bf16 [128][KPAD], zero-padded K ----------------
__global__ __launch_bounds__(256) void k_trW1(const float* __restrict__ W1,
                                              unsigned short* __restrict__ W1t) {
    int i = blockIdx.x * 256 + threadIdx.x;
    if (i >= 128 * KPAD) return;
    int c = i / KPAD, k = i % KPAD;
    unsigned short v = 0;
    if (k < KRBF) v = f2bf(W1[(size_t)k * 128 + c]);
    W1t[i] = v;
}

// ---------------- embedding gather ----------------
__global__ __launch_bounds__(256) void k_embed(const int* __restrict__ at,
                                               const float* __restrict__ W,
                                               const float* __restrict__ b,
                                               float* __restrict__ x,
                                               unsigned short* __restrict__ xh, int N) {
    int i = blockIdx.x * 256 + threadIdx.x;
    if (i >= N * HIDDEN) return;
    int n = i >> 7, c = i & 127;
    float v = W[(size_t)at[n] * HIDDEN + c] + b[c];
    x[i] = v;
    xh[(size_t)n * KXH + c] = f2bf(v);
}

// ---------------- fused RBF + Linear(720->128) via MFMA + BN + ReLU -> xh[:,128:256] ----------------
__global__ __launch_bounds__(256) void k_rbf_mfma(const float* __restrict__ pos,
                                                  const unsigned short* __restrict__ W1t,
                                                  const float* __restrict__ b1,
                                                  const float* __restrict__ g,
                                                  const float* __restrict__ bb,
                                                  const float* __restrict__ bm,
                                                  const float* __restrict__ bv,
                                                  unsigned short* __restrict__ xh, int N) {
    constexpr int LDT = 40;
    __shared__ unsigned short As[128 * LDT];
    __shared__ unsigned short Bs[128 * LDT];
    __shared__ float ps[128 * 3];
    const int tid = threadIdx.x;
    const int lane = tid & 63, wid = tid >> 6;
    const int nb = blockIdx.x * 128;
    for (int i = tid; i < 384; i += 256) {
        int n = nb + i / 3;
        ps[i] = (n < N) ? pos[(size_t)n * 3 + (i % 3)] : 1.0e9f;  // pad rows -> rbf = 0
    }
    __syncthreads();
    const int sr = tid >> 1, sk = (tid & 1) * 16;
    const int wr = (wid >> 1) * 64, wc = (wid & 1) * 64;
    const int fr = lane & 15, kg = lane >> 4;
    f32x4 acc[4][4];
#pragma unroll
    for (int i = 0; i < 4; i++)
#pragma unroll
        for (int j = 0; j < 4; j++)
#pragma unroll
            for (int r = 0; r < 4; r++) acc[i][j][r] = 0.f;
    const float p0 = ps[sr * 3], p1 = ps[sr * 3 + 1], p2 = ps[sr * 3 + 2];
    const unsigned short* bp = W1t + (size_t)sr * KPAD + sk;
    uint4 bv0 = *(const uint4*)bp, bv1 = *(const uint4*)(bp + 8);
    constexpr int NST = KPAD / 32;
    for (int ks = 0; ks < NST; ++ks) {
        unsigned short av[16];
#pragma unroll
        for (int j = 0; j < 16; j++) {
            int kglob = ks * 32 + sk + j;
            float v = 0.f;
            if (kglob < KRBF) {
                int d = kglob / 240, bin = kglob % 240;
                float mu = -30.f + (60.f / 239.f) * (float)bin;
                float p = (d == 0) ? p0 : ((d == 1) ? p1 : p2);
                float df = p - mu;
                v = __expf(-0.5f * df * df);
            }
            av[j] = f2bf(v);
        }
        __syncthreads();
        *(uint4*)&As[sr * LDT + sk] = *(const uint4*)&av[0];
        *(uint4*)&As[sr * LDT + sk + 8] = *(const uint4*)&av[8];
        *(uint4*)&Bs[sr * LDT + sk] = bv0;
        *(uint4*)&Bs[sr * LDT + sk + 8] = bv1;
        __syncthreads();
        if (ks + 1 < NST) {
            const unsigned short* bp2 = W1t + (size_t)sr * KPAD + (ks + 1) * 32 + sk;
            bv0 = *(const uint4*)bp2;
            bv1 = *(const uint4*)(bp2 + 8);
        }
        bf16x8 afr[4], bfr[4];
#pragma unroll
        for (int i = 0; i < 4; i++) {
            afr[i] = *reinterpret_cast<const bf16x8*>(&As[(wr + i * 16 + fr) * LDT + kg * 8]);
            bfr[i] = *reinterpret_cast<const bf16x8*>(&Bs[(wc + i * 16 + fr) * LDT + kg * 8]);
        }
#pragma unroll
        for (int i = 0; i < 4; i++)
#pragma unroll
            for (int j = 0; j < 4; j++)
                acc[i][j] = __builtin_amdgcn_mfma_f32_16x16x32_bf16(afr[i], bfr[j], acc[i][j], 0, 0, 0);
    }
    const int rg = lane >> 4;
#pragma unroll
    for (int i = 0; i < 4; i++) {
#pragma unroll
        for (int j = 0; j < 4; j++) {
            int col = wc + j * 16 + fr;
            float sc = g[col] * rsqrtf(bv[col] + 1e-5f);
            float sh = bb[col] - bm[col] * sc;
            float bc = b1[col];
#pragma unroll
            for (int r = 0; r < 4; r++) {
                int row = nb + wr + i * 16 + rg * 4 + r;
                if (row < N) {
                    float y = (acc[i][j][r] + bc) * sc + sh;
                    y = fmaxf(y, 0.f);
                    xh[(size_t)row * KXH + 128 + col] = f2bf(y);
                }
            }
        }
    }
}

// ---------------- shared MFMA GEMM core: C[M,N] = A[M,K] @ Bt[N,K]^T ----------------
// MODE 0: bf16 out. MODE 2: f32 out. MODE 3: bf16 out + cw[batch[row]*512+col].
// DOATT=1 (requires MODE 3, 128-col head tile): also emits a_src/a_dst[row][head].
template <int MODE, int DOATT>
__device__ __forceinline__ void gemm_core(unsigned short* As, unsigned short* Bs,
                                          const unsigned short* __restrict__ A, int lda, int M,
                                          const unsigned short* __restrict__ Bt, int ldb, int K,
                                          void* __restrict__ Cout, int ldc,
                                          const int* __restrict__ batch,
                                          const float* __restrict__ cw,
                                          int m0, int n0,
                                          const float* __restrict__ att_s,
                                          const float* __restrict__ att_d,
                                          float* __restrict__ a_src,
                                          float* __restrict__ a_dst) {
    constexpr int LDT = 40;
    const int tid = threadIdx.x;
    const int lane = tid & 63, wid = tid >> 6;
    const int wr = (wid >> 1) * 64, wc = (wid & 1) * 64;
    const int sr = tid >> 1, sk = (tid & 1) * 16;
    f32x4 acc[4][4];
#pragma unroll
    for (int i = 0; i < 4; i++)
#pragma unroll
        for (int j = 0; j < 4; j++)
#pragma unroll
            for (int r = 0; r < 4; r++) acc[i][j][r] = 0.f;
    const int nst = K / 32;
    const int arow = min(m0 + sr, M - 1);
    const unsigned short* ap = A + (size_t)arow * lda + sk;
    const unsigned short* bp = Bt + (size_t)(n0 + sr) * ldb + sk;
    uint4 av0 = *(const uint4*)ap, av1 = *(const uint4*)(ap + 8);
    uint4 bv0 = *(const uint4*)bp, bv1 = *(const uint4*)(bp + 8);
    const int fr = lane & 15, kg = lane >> 4;
    for (int ks = 0; ks < nst; ++ks) {
        __syncthreads();
        *(uint4*)&As[sr * LDT + sk] = av0;
        *(uint4*)&As[sr * LDT + sk + 8] = av1;
        *(uint4*)&Bs[sr * LDT + sk] = bv0;
        *(uint4*)&Bs[sr * LDT + sk + 8] = bv1;
        __syncthreads();
        if (ks + 1 < nst) {  // prefetch next K-step into regs, overlaps with MFMA below
            const unsigned short* ap2 = A + (size_t)arow * lda + (ks + 1) * 32 + sk;
            const unsigned short* bp2 = Bt + (size_t)(n0 + sr) * ldb + (ks + 1) * 32 + sk;
            av0 = *(const uint4*)ap2; av1 = *(const uint4*)(ap2 + 8);
            bv0 = *(const uint4*)bp2; bv1 = *(const uint4*)(bp2 + 8);
        }
        bf16x8 afr[4], bfr[4];
#pragma unroll
        for (int i = 0; i < 4; i++) {
            afr[i] = *reinterpret_cast<const bf16x8*>(&As[(wr + i * 16 + fr) * LDT + kg * 8]);
            bfr[i] = *reinterpret_cast<const bf16x8*>(&Bs[(wc + i * 16 + fr) * LDT + kg * 8]);
        }
#pragma unroll
        for (int i = 0; i < 4; i++)
#pragma unroll
            for (int j = 0; j < 4; j++)
                acc[i][j] = __builtin_amdgcn_mfma_f32_16x16x32_bf16(afr[i], bfr[j], acc[i][j], 0, 0, 0);
    }
    const int rg = lane >> 4;  // C/D: col = lane&15, row = (lane>>4)*4 + reg
    float pssum[4][4], pdsum[4][4];
#pragma unroll
    for (int i = 0; i < 4; i++)
#pragma unroll
        for (int r = 0; r < 4; r++) { pssum[i][r] = 0.f; pdsum[i][r] = 0.f; }
#pragma unroll
    for (int i = 0; i < 4; i++) {
#pragma unroll
        for (int j = 0; j < 4; j++) {
            int col = n0 + wc + j * 16 + fr;
            float asw = 0.f, adw = 0.f;
            if (DOATT) { asw = att_s[col]; adw = att_d[col]; }
#pragma unroll
            for (int r = 0; r < 4; r++) {
                int row = m0 + wr + i * 16 + rg * 4 + r;
                if (row < M) {
                    float vv = acc[i][j][r];
                    if (MODE == 2) {
                        ((float*)Cout)[(size_t)row * ldc + col] = vv;
                    } else if (MODE == 3) {
                        vv += cw[(size_t)batch[row] * 512 + col];
                        ((unsigned short*)Cout)[(size_t)row * ldc + col] = f2bf(vv);
                        if (DOATT) { pssum[i][r] += vv * asw; pdsum[i][r] += vv * adw; }
                    } else {
                        ((unsigned short*)Cout)[(size_t)row * ldc + col] = f2bf(vv);
                    }
                }
            }
        }
    }
    if (DOATT) {
        __syncthreads();  // LDS (As) is dead; reuse for cross-wave att combine
        float* lat = (float*)As;  // [4 waves][64 rows][2]
#pragma unroll
        for (int i = 0; i < 4; i++) {
#pragma unroll
            for (int r = 0; r < 4; r++) {
                float s = pssum[i][r], d = pdsum[i][r];
#pragma unroll
                for (int dd = 1; dd < 16; dd <<= 1) {
                    s += __shfl_xor(s, dd);
                    d += __shfl_xor(d, dd);
                }
                if (fr == 0) {
                    int k = i * 16 + rg * 4 + r;
                    lat[(wid * 64 + k) * 2] = s;
                    lat[(wid * 64 + k) * 2 + 1] = d;
                }
            }
        }
        __syncthreads();
        if ((wid & 1) == 0) {
            int k = lane;
            int row = m0 + (wid >> 1) * 64 + k;
            if (row < M) {
                float s = lat[(wid * 64 + k) * 2] + lat[((wid + 1) * 64 + k) * 2];
                float d = lat[(wid * 64 + k) * 2 + 1] + lat[((wid + 1) * 64 + k) * 2 + 1];
                int head = n0 >> 7;
                a_src[(size_t)row * 4 + head] = s;
                a_dst[(size_t)row * 4 + head] = d;
            }
        }
    }
}

// GAT per-layer node GEMM (MODE 3 + fused attention logits)
__global__ __launch_bounds__(256) void k_gemm3(const unsigned short* __restrict__ A, int M,
                                               const unsigned short* __restrict__ Bt,
                                               unsigned short* __restrict__ C,
                                               const int* __restrict__ batch,
                                               const float* __restrict__ cw,
                                               const float* __restrict__ att_s,
                                               const float* __restrict__ att_d,
                                               float* __restrict__ a_src,
                                               float* __restrict__ a_dst) {
    constexpr int LDT = 40;
    __shared__ unsigned short As[128 * LDT];
    __shared__ unsigned short Bs[128 * LDT];
    gemm_core<3, 1>(As, Bs, A, KXH, M, Bt, KXH, KXH, C, 512, batch, cw,
                    blockIdx.x * 128, blockIdx.y * 128, att_s, att_d, a_src, a_dst);
}

// merged weight-prep GEMMs: z<3 -> Bc[l][:,128:256] = Wc[l]^T @ W2^T; z>=3 -> cW[l] = cpre @ Wc[l]
__global__ __launch_bounds__(256) void k_prep(const unsigned short* __restrict__ gatWt,
                                              const unsigned short* __restrict__ W2bf,
                                              const unsigned short* __restrict__ cpre,
                                              unsigned short* __restrict__ Bc,
                                              float* __restrict__ cW, int NG) {
    constexpr int LDT = 40;
    __shared__ unsigned short As[128 * LDT];
    __shared__ unsigned short Bs[128 * LDT];
    int z = blockIdx.z;
    if (z < 3) {
        if (blockIdx.y != 0) return;
        gemm_core<0, 0>(As, Bs, gatWt + (size_t)z * 512 * 2176 + 128, 2176, 512,
                        W2bf, CTXD, CTXD, Bc + (size_t)z * 512 * KXH + 128, KXH,
                        nullptr, nullptr, blockIdx.x * 128, 0,
                        nullptr, nullptr, nullptr, nullptr);
    } else {
        if (blockIdx.x != 0) return;
        int zz = z - 3;
        gemm_core<2, 0>(As, Bs, cpre, CTXD, NG, gatWt + (size_t)zz * 512 * 2176 + 128, 2176, CTXD,
                        cW + (size_t)zz * NG * 512, 512, nullptr, nullptr, 0, blockIdx.y * 128,
                        nullptr, nullptr, nullptr, nullptr);
    }
}

// ---------------- CSR build ----------------
__global__ void k_cnt_init(int* cnt, int N) {
    int i = blockIdx.x * 256 + threadIdx.x;
    if (i < N) cnt[i] = 1;  // self-loop
}
__global__ void k_cnt(const int* __restrict__ ei, int E, int* cnt) {
    int i = blockIdx.x * 256 + threadIdx.x;
    if (i < E) atomicAdd(&cnt[ei[E + i]], 1);
}
__global__ __launch_bounds__(1024) void k_scan(const int* __restrict__ cnt, int* __restrict__ rowptr,
                                               int* __restrict__ cursor, int n) {
    __shared__ int wsum[16];
    __shared__ int carry;
    int tid = threadIdx.x, lane = tid & 63, wid = tid >> 6;
    if (tid == 0) carry = 0;
    __syncthreads();
    for (int basei = 0; basei < n; basei += 1024) {
        int i = basei + tid;
        int v = (i < n) ? cnt[i] : 0;
        int s = v;
#pragma unroll
        for (int d = 1; d < 64; d <<= 1) {
            int t = __shfl_up(s, (unsigned)d);
            if (lane >= d) s += t;
        }
        if (lane == 63) wsum[wid] = s;
        __syncthreads();
        if (wid == 0 && lane < 16) {
            int ws = wsum[lane]; int t = ws;
#pragma unroll
            for (int d = 1; d < 16; d <<= 1) {
                int u = __shfl_up(t, (unsigned)d);
                if (lane >= d) t += u;
            }
            wsum[lane] = t - ws;  // exclusive wave offsets
        }
        __syncthreads();
        int excl = carry + wsum[wid] + (s - v);
        if (i < n) { rowptr[i] = excl; cursor[i] = excl; }
        __syncthreads();
        if (tid == 1023) carry += wsum[15] + s;
        __syncthreads();
    }
    if (tid == 0) rowptr[n] = carry;
}
__global__ void k_fill(const int* __restrict__ ei, int E, int N, int* cursor, int* csrc) {
    int i = blockIdx.x * 256 + threadIdx.x;
    if (i >= E + N) return;
    int s, d;
    if (i < E) { s = ei[i]; d = ei[E + i]; }
    else { s = i - E; d = s; }
    int slot = atomicAdd(&cursor[d], 1);
    csrc[slot] = s;
}

// ---------------- GAT aggregation: one-pass softmax + LDS-staged gather ----------------
__global__ __launch_bounds__(256) void k_agg(const int* __restrict__ rowptr,
                                             const int* __restrict__ csrc,
                                             const float* __restrict__ asrc,
                                             const float* __restrict__ adstv,
                                             const unsigned short* __restrict__ xs,
                                             const float* __restrict__ gbias,
                                             const float* __restrict__ bg,
                                             const float* __restrict__ bb,
                                             const float* __restrict__ bm,
                                             const float* __restrict__ bv,
                                             float* __restrict__ x,
                                             unsigned short* __restrict__ xh, int N) {
    __shared__ float wsh[4][64][4];
    __shared__ int ssh[4][64];
    int tid = threadIdx.x, lane = tid & 63, wid = tid >> 6;
    int n = blockIdx.x * 4 + wid;
    if (n >= N) return;
    int beg = rowptr[n], end = rowptr[n + 1];
    float4 ad = *(const float4*)(adstv + (size_t)n * 4);
    int nch = (end - beg + 63) >> 6;
    // phase A: online per-head max & denom (lane i owns edge beg+i of each chunk)
    float m0 = -1e30f, m1 = -1e30f, m2 = -1e30f, m3 = -1e30f;
    float s0 = 0.f, s1 = 0.f, s2 = 0.f, s3 = 0.f;
    float a0 = -1e30f, a1 = -1e30f, a2 = -1e30f, a3 = -1e30f;  // persisted (single-chunk reuse)
    int sv = 0;
    for (int base = beg; base < end; base += 64) {
        int idx = base + lane;
        float b0 = -1e30f, b1 = -1e30f, b2 = -1e30f, b3 = -1e30f;
        int s = 0;
        if (idx < end) {
            s = csrc[idx];
            float4 t = *(const float4*)(asrc + (size_t)s * 4);
            b0 = t.x + ad.x; b0 = b0 > 0.f ? b0 : 0.2f * b0;
            b1 = t.y + ad.y; b1 = b1 > 0.f ? b1 : 0.2f * b1;
            b2 = t.z + ad.z; b2 = b2 > 0.f ? b2 : 0.2f * b2;
            b3 = t.w + ad.w; b3 = b3 > 0.f ? b3 : 0.2f * b3;
        }
        float c0 = b0, c1 = b1, c2 = b2, c3 = b3;
#pragma unroll
        for (int d = 1; d < 64; d <<= 1) {
            c0 = fmaxf(c0, __shfl_xor(c0, d));
            c1 = fmaxf(c1, __shfl_xor(c1, d));
            c2 = fmaxf(c2, __shfl_xor(c2, d));
            c3 = fmaxf(c3, __shfl_xor(c3, d));
        }
        float nm0 = fmaxf(m0, c0), nm1 = fmaxf(m1, c1), nm2 = fmaxf(m2, c2), nm3 = fmaxf(m3, c3);
        float e0 = (idx < end) ? __expf(b0 - nm0) : 0.f;
        float e1 = (idx < end) ? __expf(b1 - nm1) : 0.f;
        float e2 = (idx < end) ? __expf(b2 - nm2) : 0.f;
        float e3 = (idx < end) ? __expf(b3 - nm3) : 0.f;
#pragma unroll
        for (int d = 1; d < 64; d <<= 1) {
            e0 += __shfl_xor(e0, d); e1 += __shfl_xor(e1, d);
            e2 += __shfl_xor(e2, d); e3 += __shfl_xor(e3, d);
        }
        s0 = s0 * __expf(m0 - nm0) + e0; m0 = nm0;
        s1 = s1 * __expf(m1 - nm1) + e1; m1 = nm1;
        s2 = s2 * __expf(m2 - nm2) + e2; m2 = nm2;
        s3 = s3 * __expf(m3 - nm3) + e3; m3 = nm3;
        a0 = b0; a1 = b1; a2 = b2; a3 = b3; sv = s;
    }
    float i0 = 1.f / fmaxf(s0, 1e-16f), i1 = 1.f / fmaxf(s1, 1e-16f);
    float i2 = 1.f / fmaxf(s2, 1e-16f), i3 = 1.f / fmaxf(s3, 1e-16f);
    // phase B: weighted gather, per-edge weights staged in LDS (wave-private)
    const int h = lane >> 4, c0i = (lane & 15) * 8;
    float acc[8];
#pragma unroll
    for (int j = 0; j < 8; j++) acc[j] = 0.f;
    for (int base = beg; base < end; base += 64) {
        int s; float w0, w1, w2, w3;
        if (nch == 1) {
            s = sv;
            w0 = __expf(a0 - m0) * i0; w1 = __expf(a1 - m1) * i1;
            w2 = __expf(a2 - m2) * i2; w3 = __expf(a3 - m3) * i3;
        } else {
            int idx = base + lane;
            float b0 = -1e30f, b1 = -1e30f, b2 = -1e30f, b3 = -1e30f;
            s = 0;
            if (idx < end) {
                s = csrc[idx];
                float4 t = *(const float4*)(asrc + (size_t)s * 4);
                b0 = t.x + ad.x; b0 = b0 > 0.f ? b0 : 0.2f * b0;
                b1 = t.y + ad.y; b1 = b1 > 0.f ? b1 : 0.2f * b1;
                b2 = t.z + ad.z; b2 = b2 > 0.f ? b2 : 0.2f * b2;
                b3 = t.w + ad.w; b3 = b3 > 0.f ? b3 : 0.2f * b3;
            }
            w0 = __expf(b0 - m0) * i0; w1 = __expf(b1 - m1) * i1;
            w2 = __expf(b2 - m2) * i2; w3 = __expf(b3 - m3) * i3;
        }
        ssh[wid][lane] = s;
        wsh[wid][lane][0] = w0; wsh[wid][lane][1] = w1;
        wsh[wid][lane][2] = w2; wsh[wid][lane][3] = w3;
        int cnt = min(64, end - base);
        int i = 0;
        for (; i + 2 <= cnt; i += 2) {
            int sa = ssh[wid][i], sb = ssh[wid][i + 1];
            float wa = wsh[wid][i][h], wb = wsh[wid][i + 1][h];
            uint4 ra = *(const uint4*)(xs + ((size_t)sa << 9) + (h << 7) + c0i);
            uint4 rb = *(const uint4*)(xs + ((size_t)sb << 9) + (h << 7) + c0i);
            const unsigned short* qa = (const unsigned short*)&ra;
            const unsigned short* qb = (const unsigned short*)&rb;
#pragma unroll
            for (int j = 0; j < 8; j++) acc[j] += wa * bf2f(qa[j]);
#pragma unroll
            for (int j = 0; j < 8; j++) acc[j] += wb * bf2f(qb[j]);
        }
        if (i < cnt) {
            int sa = ssh[wid][i];
            float wa = wsh[wid][i][h];
            uint4 ra = *(const uint4*)(xs + ((size_t)sa << 9) + (h << 7) + c0i);
            const unsigned short* qa = (const unsigned short*)&ra;
#pragma unroll
            for (int j = 0; j < 8; j++) acc[j] += wa * bf2f(qa[j]);
        }
    }
    // head mean across lanes (h = lane>>4)
#pragma unroll
    for (int j = 0; j < 8; j++) {
        acc[j] += __shfl_xor(acc[j], 16);
        acc[j] += __shfl_xor(acc[j], 32);
    }
    if (lane < 16) {
#pragma unroll
        for (int j = 0; j < 8; j++) {
            int c = c0i + j;
            float t = acc[j] * 0.25f + gbias[c];
            float sc = bg[c] * rsqrtf(bv[c] + 1e-5f);
            float y = (t - bm[c]) * sc + bb[c];
            float ge = 0.5f * y * (1.f + erff(y * 0.70710678118f));
            float xn = x[(size_t)n * 128 + c] + ge;
            x[(size_t)n * 128 + c] = xn;
            xh[(size_t)n * KXH + c] = f2bf(xn);
        }
    }
}

// ---------------- fused pool + final linear ----------------
__global__ __launch_bounds__(256) void k_pool(const float* __restrict__ x,
                                              const int* __restrict__ batch,
                                              const float* __restrict__ W,
                                              const float* __restrict__ bo,
                                              float* __restrict__ out, int N) {
    __shared__ float xg[128];
    __shared__ float tmp[256];
    __shared__ int bounds[2];
    int g = blockIdx.x, tid = threadIdx.x;
    if (tid < 2) {
        int key = g + tid, lo = 0, hi = N;
        while (lo < hi) { int mid = (lo + hi) >> 1; if (batch[mid] < key) lo = mid + 1; else hi = mid; }
        bounds[tid] = lo;
    }
    __syncthreads();
    int s = bounds[0], e = bounds[1];
    int c = tid & 127, rgp = tid >> 7;
    float a = 0.f;
    for (int n = s + rgp; n < e; n += 2) a += x[(size_t)n * 128 + c];
    tmp[tid] = a;
    __syncthreads();
    if (tid < 128) xg[tid] = tmp[tid] + tmp[tid + 128];
    __syncthreads();
    float cntf = (float)(e - s);
    for (int j = tid; j < 1024; j += 256) {
        float o = cntf * bo[j];
        for (int cc = 0; cc < 128; cc++) o += xg[cc] * W[(size_t)cc * 1024 + j];
        out[(size_t)g * 1024 + j] = o;
    }
}

extern "C" void kernel_launch(void* const* d_in, const int* in_sizes, int n_in,
                              void* d_out, int out_size, void* d_ws, size_t ws_size,
                              hipStream_t stream) {
    const int N = in_sizes[0];
    const int E = in_sizes[2] / 2;
    const int NG = in_sizes[5] / CTXD;
    const int* at = (const int*)d_in[0];
    const float* pos = (const float*)d_in[1];
    const int* ei = (const int*)d_in[2];
    const int* batch = (const int*)d_in[4];
    const float* ctx = (const float*)d_in[5];
    const float* embW = (const float*)d_in[6];
    const float* embB = (const float*)d_in[7];
    const float* W1 = (const float*)d_in[8];
    const float* b1 = (const float*)d_in[9];
    const float* rg = (const float*)d_in[10];
    const float* rb = (const float*)d_in[11];
    const float* rm = (const float*)d_in[12];
    const float* rv = (const float*)d_in[13];
    const float* W2 = (const float*)d_in[14];
    const float* b2 = (const float*)d_in[15];
    const float* gatW = (const float*)d_in[16];
    const float* atts = (const float*)d_in[17];
    const float* attd = (const float*)d_in[18];
    const float* gbias = (const float*)d_in[19];
    const float* bg = (const float*)d_in[20];
    const float* bbb = (const float*)d_in[21];
    const float* bm = (const float*)d_in[22];
    const float* bv = (const float*)d_in[23];
    const float* outW = (const float*)d_in[24];
    const float* outb = (const float*)d_in[25];
    float* out = (float*)d_out;

    char* basep = (char*)d_ws;
    size_t off = 0;
    auto alloc = [&](size_t bytes) -> char* {
        char* p = basep + off;
        off = (off + bytes + 255) & ~(size_t)255;
        return p;
    };
    unsigned short* xh = (unsigned short*)alloc((size_t)N * KXH * 2);
    float* x = (float*)alloc((size_t)N * 128 * 4);
    unsigned short* xs = (unsigned short*)alloc((size_t)N * 512 * 2);
    float* a_src = (float*)alloc((size_t)N * 4 * 4);
    float* a_dst = (float*)alloc((size_t)N * 4 * 4);
    int* cnt = (int*)alloc((size_t)N * 4);
    int* rowptr = (int*)alloc((size_t)(N + 1) * 4);
    int* cursor = (int*)alloc((size_t)N * 4);
    int* csrc = (int*)alloc((size_t)(E + N) * 4);
    unsigned short* gatWt = (unsigned short*)alloc((size_t)NLAYERS * 512 * 2176 * 2);
    unsigned short* W1t = (unsigned short*)alloc((size_t)128 * KPAD * 2);
    unsigned short* W2bf = (unsigned short*)alloc((size_t)128 * CTXD * 2);
    unsigned short* cpre = (unsigned short*)alloc((size_t)NG * CTXD * 2);
    unsigned short* Bc = (unsigned short*)alloc((size_t)NLAYERS * 512 * KXH * 2);
    float* cW = (float*)alloc((size_t)NLAYERS * NG * 512 * 4);
    (void)ws_size; (void)n_in; (void)out_size;

    // ---- weight prep ----
    {
        dim3 b(32, 8);
        dim3 g1((512 + 31) / 32, (2176 + 31) / 32, NLAYERS);
        k_tr<<<g1, b, 0, stream>>>(gatW, gatWt, 2176, 512);
        k_trW1<<<(128 * KPAD + 255) / 256, 256, 0, stream>>>(W1, W1t);
        k_w2bf<<<(128 * CTXD + 255) / 256, 256, 0, stream>>>(W2, W2bf);
        k_cpre<<<(NG * CTXD + 255) / 256, 256, 0, stream>>>(ctx, b2, cpre, NG);
        k_bccopy<<<(NLAYERS * 512 * 128 + 255) / 256, 256, 0, stream>>>(gatWt, Bc);
        dim3 gp(4, 4, 6);
        k_prep<<<gp, 256, 0, stream>>>(gatWt, W2bf, cpre, Bc, cW, NG);
    }
    // ---- node features ----
    k_embed<<<(N * 128 + 255) / 256, 256, 0, stream>>>(at, embW, embB, x, xh, N);
    k_rbf_mfma<<<(N + 127) / 128, 256, 0, stream>>>(pos, W1t, b1, rg, rb, rm, rv, xh, N);
    // ---- CSR (dst-sorted incoming edges incl. self-loops) ----
    k_cnt_init<<<(N + 255) / 256, 256, 0, stream>>>(cnt, N);
    k_cnt<<<(E + 255) / 256, 256, 0, stream>>>(ei, E, cnt);
    k_scan<<<1, 1024, 0, stream>>>(cnt, rowptr, cursor, N);
    k_fill<<<(E + N + 255) / 256, 256, 0, stream>>>(ei, E, N, cursor, csrc);
    // ---- GAT layers ----
    {
        dim3 g((N + 127) / 128, 4, 1);
        for (int l = 0; l < NLAYERS; l++) {
            k_gemm3<<<g, 256, 0, stream>>>(xh, N, Bc + (size_t)l * 512 * KXH,
                                           xs, batch, cW + (size_t)l * NG * 512,
                                           atts + l * 512, attd + l * 512, a_src, a_dst);
            k_agg<<<(N + 3) / 4, 256, 0, stream>>>(rowptr, csrc, a_src, a_dst, xs,
                                                   gbias + l * 128, bg + l * 128, bbb + l * 128,
                                                   bm + l * 128, bv + l * 128, x, xh, N);
        }
    }
    k_pool<<<NG, 256, 0, stream>>>(x, batch, outW, outb, out, N);
}

// Round 10
// 456.740 us; speedup vs baseline: 1.1482x; 1.0393x over previous
//
#include <hip/hip_runtime.h>
#include <hip/hip_bf16.h>
#include <cstdint>

constexpr int HIDDEN = 128, CTXD = 2048, HEADS = 4, NLAYERS = 3;
constexpr int KRBF = 720, KPAD = 736;  // 736 = 23 * 32
constexpr int KXH = 256;               // concat [x | h] K-dim

typedef __bf16 bf16x8 __attribute__((ext_vector_type(8)));
typedef float f32x4 __attribute__((ext_vector_type(4)));

static __device__ __forceinline__ unsigned short f2bf(float f) {
    union { float f; unsigned u; } v; v.f = f;
    unsigned r = v.u + 0x7fffu + ((v.u >> 16) & 1u);
    return (unsigned short)(r >> 16);
}
static __device__ __forceinline__ float bf2f(unsigned short s) {
    union { unsigned u; float f; } v; v.u = ((unsigned)s) << 16; return v.f;
}

// ================= merged input-only prep (flat-grid partitioned) =================
// parts: [0] W1 -> W1t bf16 [128][KPAD]; [1] W2 -> bf16; [2] ctx+b2 -> cpre bf16;
// [3] cnt init = 1; [4] embedding -> x, xh[:,0:128]; [5] gatW transpose -> gatWt bf16
__global__ __launch_bounds__(256) void k_misc(const float* __restrict__ W1,
                                              unsigned short* __restrict__ W1t,
                                              const float* __restrict__ W2,
                                              unsigned short* __restrict__ W2bf,
                                              const float* __restrict__ ctx,
                                              const float* __restrict__ b2,
                                              unsigned short* __restrict__ cpre,
                                              int* __restrict__ cnt,
                                              const int* __restrict__ at,
                                              const float* __restrict__ embW,
                                              const float* __restrict__ embB,
                                              float* __restrict__ x,
                                              unsigned short* __restrict__ xh,
                                              const float* __restrict__ gatW,
                                              unsigned short* __restrict__ gatWt,
                                              int N, int NG,
                                              int e0, int e1, int e2, int e3, int e4) {
    __shared__ unsigned short t[32][34];
    int b = blockIdx.x, tid = threadIdx.x;
    if (b < e0) {  // W1t
        int i = b * 256 + tid;
        if (i < 128 * KPAD) {
            int c = i / KPAD, k = i % KPAD;
            W1t[i] = (k < KRBF) ? f2bf(W1[(size_t)k * 128 + c]) : (unsigned short)0;
        }
    } else if (b < e1) {  // W2bf
        int i = (b - e0) * 256 + tid;
        if (i < 128 * CTXD) W2bf[i] = f2bf(W2[i]);
    } else if (b < e2) {  // cpre
        int i = (b - e1) * 256 + tid;
        if (i < NG * CTXD) cpre[i] = f2bf(ctx[i] + b2[i % CTXD]);
    } else if (b < e3) {  // cnt init (self-loop)
        int i = (b - e2) * 256 + tid;
        if (i < N) cnt[i] = 1;
    } else if (b < e4) {  // embed
        int i = (b - e3) * 256 + tid;
        if (i < N * HIDDEN) {
            int n = i >> 7, c = i & 127;
            float v = embW[(size_t)at[n] * HIDDEN + c] + embB[c];
            x[i] = v;
            xh[(size_t)n * KXH + c] = f2bf(v);
        }
    } else {  // gatW transpose: f32 [3][2176][512] -> bf16 [3][512][2176]
        int idx = b - e4;
        int bz = idx / (16 * 68);
        int rem = idx % (16 * 68);
        int bx = rem % 16, by = rem / 16;
        int tx = tid & 31, ty = tid >> 5;
        const int R = 2176, C = 512;
        int c0 = bx * 32, r0 = by * 32;
        const float* s = gatW + (size_t)bz * R * C;
        unsigned short* d = gatWt + (size_t)bz * R * C;
        for (int rr = ty; rr < 32; rr += 8) {
            int r = r0 + rr, c = c0 + tx;
            t[rr][tx] = f2bf(s[(size_t)r * C + c]);
        }
        __syncthreads();
        for (int rr = ty; rr < 32; rr += 8) {
            int c = c0 + rr, r = r0 + tx;
            d[(size_t)c * R + r] = t[tx][rr];
        }
    }
}

// ---------------- shared MFMA GEMM core: C[M,N] = A[M,K] @ Bt[N,K]^T ----------------
// MODE 0: bf16 out. MODE 2: f32 out. MODE 3: bf16 out + cw[batch[row]*512+col].
// DOATT=1 (requires MODE 3, 128-col head tile): also emits a_src/a_dst[row][head].
template <int MODE, int DOATT>
__device__ __forceinline__ void gemm_core(unsigned short* As, unsigned short* Bs,
                                          const unsigned short* __restrict__ A, int lda, int M,
                                          const unsigned short* __restrict__ Bt, int ldb, int K,
                                          void* __restrict__ Cout, int ldc,
                                          const int* __restrict__ batch,
                                          const float* __restrict__ cw,
                                          int m0, int n0,
                                          const float* __restrict__ att_s,
                                          const float* __restrict__ att_d,
                                          float* __restrict__ a_src,
                                          float* __restrict__ a_dst) {
    constexpr int LDT = 40;
    const int tid = threadIdx.x;
    const int lane = tid & 63, wid = tid >> 6;
    const int wr = (wid >> 1) * 64, wc = (wid & 1) * 64;
    const int sr = tid >> 1, sk = (tid & 1) * 16;
    f32x4 acc[4][4];
#pragma unroll
    for (int i = 0; i < 4; i++)
#pragma unroll
        for (int j = 0; j < 4; j++)
#pragma unroll
            for (int r = 0; r < 4; r++) acc[i][j][r] = 0.f;
    const int nst = K / 32;
    const int arow = min(m0 + sr, M - 1);
    const unsigned short* ap = A + (size_t)arow * lda + sk;
    const unsigned short* bp = Bt + (size_t)(n0 + sr) * ldb + sk;
    uint4 av0 = *(const uint4*)ap, av1 = *(const uint4*)(ap + 8);
    uint4 bv0 = *(const uint4*)bp, bv1 = *(const uint4*)(bp + 8);
    const int fr = lane & 15, kg = lane >> 4;
    for (int ks = 0; ks < nst; ++ks) {
        __syncthreads();
        *(uint4*)&As[sr * LDT + sk] = av0;
        *(uint4*)&As[sr * LDT + sk + 8] = av1;
        *(uint4*)&Bs[sr * LDT + sk] = bv0;
        *(uint4*)&Bs[sr * LDT + sk + 8] = bv1;
        __syncthreads();
        if (ks + 1 < nst) {  // prefetch next K-step into regs, overlaps with MFMA below
            const unsigned short* ap2 = A + (size_t)arow * lda + (ks + 1) * 32 + sk;
            const unsigned short* bp2 = Bt + (size_t)(n0 + sr) * ldb + (ks + 1) * 32 + sk;
            av0 = *(const uint4*)ap2; av1 = *(const uint4*)(ap2 + 8);
            bv0 = *(const uint4*)bp2; bv1 = *(const uint4*)(bp2 + 8);
        }
        bf16x8 afr[4], bfr[4];
#pragma unroll
        for (int i = 0; i < 4; i++) {
            afr[i] = *reinterpret_cast<const bf16x8*>(&As[(wr + i * 16 + fr) * LDT + kg * 8]);
            bfr[i] = *reinterpret_cast<const bf16x8*>(&Bs[(wc + i * 16 + fr) * LDT + kg * 8]);
        }
#pragma unroll
        for (int i = 0; i < 4; i++)
#pragma unroll
            for (int j = 0; j < 4; j++)
                acc[i][j] = __builtin_amdgcn_mfma_f32_16x16x32_bf16(afr[i], bfr[j], acc[i][j], 0, 0, 0);
    }
    const int rg = lane >> 4;  // C/D: col = lane&15, row = (lane>>4)*4 + reg
    float pssum[4][4], pdsum[4][4];
#pragma unroll
    for (int i = 0; i < 4; i++)
#pragma unroll
        for (int r = 0; r < 4; r++) { pssum[i][r] = 0.f; pdsum[i][r] = 0.f; }
#pragma unroll
    for (int i = 0; i < 4; i++) {
#pragma unroll
        for (int j = 0; j < 4; j++) {
            int col = n0 + wc + j * 16 + fr;
            float asw = 0.f, adw = 0.f;
            if (DOATT) { asw = att_s[col]; adw = att_d[col]; }
#pragma unroll
            for (int r = 0; r < 4; r++) {
                int row = m0 + wr + i * 16 + rg * 4 + r;
                if (row < M) {
                    float vv = acc[i][j][r];
                    if (MODE == 2) {
                        ((float*)Cout)[(size_t)row * ldc + col] = vv;
                    } else if (MODE == 3) {
                        vv += cw[(size_t)batch[row] * 512 + col];
                        ((unsigned short*)Cout)[(size_t)row * ldc + col] = f2bf(vv);
                        if (DOATT) { pssum[i][r] += vv * asw; pdsum[i][r] += vv * adw; }
                    } else {
                        ((unsigned short*)Cout)[(size_t)row * ldc + col] = f2bf(vv);
                    }
                }
            }
        }
    }
    if (DOATT) {
        __syncthreads();  // LDS (As) is dead; reuse for cross-wave att combine
        float* lat = (float*)As;  // [4 waves][64 rows][2]
#pragma unroll
        for (int i = 0; i < 4; i++) {
#pragma unroll
            for (int r = 0; r < 4; r++) {
                float s = pssum[i][r], d = pdsum[i][r];
#pragma unroll
                for (int dd = 1; dd < 16; dd <<= 1) {
                    s += __shfl_xor(s, dd);
                    d += __shfl_xor(d, dd);
                }
                if (fr == 0) {
                    int k = i * 16 + rg * 4 + r;
                    lat[(wid * 64 + k) * 2] = s;
                    lat[(wid * 64 + k) * 2 + 1] = d;
                }
            }
        }
        __syncthreads();
        if ((wid & 1) == 0) {
            int k = lane;
            int row = m0 + (wid >> 1) * 64 + k;
            if (row < M) {
                float s = lat[(wid * 64 + k) * 2] + lat[((wid + 1) * 64 + k) * 2];
                float d = lat[(wid * 64 + k) * 2 + 1] + lat[((wid + 1) * 64 + k) * 2 + 1];
                int head = n0 >> 7;
                a_src[(size_t)row * 4 + head] = s;
                a_dst[(size_t)row * 4 + head] = d;
            }
        }
    }
}

// ============ merged: RBF-MFMA (blocks [0,nbRbf)) + prep GEMMs + Bc copy ============
__global__ __launch_bounds__(256) void k_rbfprep(const float* __restrict__ pos,
                                                 const unsigned short* __restrict__ W1t,
                                                 const float* __restrict__ b1,
                                                 const float* __restrict__ g,
                                                 const float* __restrict__ bb,
                                                 const float* __restrict__ bm,
                                                 const float* __restrict__ bv,
                                                 unsigned short* __restrict__ xh,
                                                 const unsigned short* __restrict__ gatWt,
                                                 const unsigned short* __restrict__ W2bf,
                                                 const unsigned short* __restrict__ cpre,
                                                 unsigned short* __restrict__ Bc,
                                                 float* __restrict__ cW,
                                                 int N, int NG, int nbRbf) {
    constexpr int LDT = 40;
    __shared__ unsigned short As[128 * LDT];
    __shared__ unsigned short Bs[128 * LDT];
    __shared__ float ps[128 * 3];
    const int bid = blockIdx.x;
    const int tid = threadIdx.x;
    if (bid >= nbRbf) {
        int idx = bid - nbRbf;
        if (idx < 12) {  // Bc[l][:,128:256] = Wc[l]^T @ W2^T
            int z = idx >> 2, mt = idx & 3;
            gemm_core<0, 0>(As, Bs, gatWt + (size_t)z * 512 * 2176 + 128, 2176, 512,
                            W2bf, CTXD, CTXD, Bc + (size_t)z * 512 * KXH + 128, KXH,
                            nullptr, nullptr, mt * 128, 0, nullptr, nullptr, nullptr, nullptr);
        } else if (idx < 24) {  // cW[l] = cpre @ Wc[l]
            int z = (idx - 12) >> 2, nt = (idx - 12) & 3;
            gemm_core<2, 0>(As, Bs, cpre, CTXD, NG, gatWt + (size_t)z * 512 * 2176 + 128, 2176,
                            CTXD, cW + (size_t)z * NG * 512, 512, nullptr, nullptr, 0, nt * 128,
                            nullptr, nullptr, nullptr, nullptr);
        } else {  // Bc[l][o][0:128] = gatWt[l][o][0:128]
            int i = (idx - 24) * 256 + tid;
            if (i < NLAYERS * 512 * 128) {
                int lo = i >> 7, k = i & 127;
                Bc[(size_t)lo * KXH + k] = gatWt[(size_t)lo * 2176 + k];
            }
        }
        return;
    }
    // ---- RBF + Linear(720->128) via MFMA + BN + ReLU -> xh[:,128:256] ----
    const int lane = tid & 63, wid = tid >> 6;
    const int nb = bid * 128;
    for (int i = tid; i < 384; i += 256) {
        int n = nb + i / 3;
        ps[i] = (n < N) ? pos[(size_t)n * 3 + (i % 3)] : 1.0e9f;  // pad rows -> rbf = 0
    }
    __syncthreads();
    const int sr = tid >> 1, sk = (tid & 1) * 16;
    const int wr = (wid >> 1) * 64, wc = (wid & 1) * 64;
    const int fr = lane & 15, kg = lane >> 4;
    f32x4 acc[4][4];
#pragma unroll
    for (int i = 0; i < 4; i++)
#pragma unroll
        for (int j = 0; j < 4; j++)
#pragma unroll
            for (int r = 0; r < 4; r++) acc[i][j][r] = 0.f;
    const float p0 = ps[sr * 3], p1 = ps[sr * 3 + 1], p2 = ps[sr * 3 + 2];
    const unsigned short* bp = W1t + (size_t)sr * KPAD + sk;
    uint4 bv0 = *(const uint4*)bp, bv1 = *(const uint4*)(bp + 8);
    constexpr int NST = KPAD / 32;
    for (int ks = 0; ks < NST; ++ks) {
        unsigned short av[16];
#pragma unroll
        for (int j = 0; j < 16; j++) {
            int kglob = ks * 32 + sk + j;
            float v = 0.f;
            if (kglob < KRBF) {
                int d = kglob / 240, bin = kglob % 240;
                float mu = -30.f + (60.f / 239.f) * (float)bin;
                float p = (d == 0) ? p0 : ((d == 1) ? p1 : p2);
                float df = p - mu;
                v = __expf(-0.5f * df * df);
            }
            av[j] = f2bf(v);
        }
        __syncthreads();
        *(uint4*)&As[sr * LDT + sk] = *(const uint4*)&av[0];
        *(uint4*)&As[sr * LDT + sk + 8] = *(const uint4*)&av[8];
        *(uint4*)&Bs[sr * LDT + sk] = bv0;
        *(uint4*)&Bs[sr * LDT + sk + 8] = bv1;
        __syncthreads();
        if (ks + 1 < NST) {
            const unsigned short* bp2 = W1t + (size_t)sr * KPAD + (ks + 1) * 32 + sk;
            bv0 = *(const uint4*)bp2;
            bv1 = *(const uint4*)(bp2 + 8);
        }
        bf16x8 afr[4], bfr[4];
#pragma unroll
        for (int i = 0; i < 4; i++) {
            afr[i] = *reinterpret_cast<const bf16x8*>(&As[(wr + i * 16 + fr) * LDT + kg * 8]);
            bfr[i] = *reinterpret_cast<const bf16x8*>(&Bs[(wc + i * 16 + fr) * LDT + kg * 8]);
        }
#pragma unroll
        for (int i = 0; i < 4; i++)
#pragma unroll
            for (int j = 0; j < 4; j++)
                acc[i][j] = __builtin_amdgcn_mfma_f32_16x16x32_bf16(afr[i], bfr[j], acc[i][j], 0, 0, 0);
    }
    const int rg = lane >> 4;
#pragma unroll
    for (int i = 0; i < 4; i++) {
#pragma unroll
        for (int j = 0; j < 4; j++) {
            int col = wc + j * 16 + fr;
            float sc = g[col] * rsqrtf(bv[col] + 1e-5f);
            float sh = bb[col] - bm[col] * sc;
            float bc = b1[col];
#pragma unroll
            for (int r = 0; r < 4; r++) {
                int row = nb + wr + i * 16 + rg * 4 + r;
                if (row < N) {
                    float y = (acc[i][j][r] + bc) * sc + sh;
                    y = fmaxf(y, 0.f);
                    xh[(size_t)row * KXH + 128 + col] = f2bf(y);
                }
            }
        }
    }
}

// GAT per-layer node GEMM (MODE 3 + fused attention logits)
__global__ __launch_bounds__(256) void k_gemm3(const unsigned short* __restrict__ A, int M,
                                               const unsigned short* __restrict__ Bt,
                                               unsigned short* __restrict__ C,
                                               const int* __restrict__ batch,
                                               const float* __restrict__ cw,
                                               const float* __restrict__ att_s,
                                               const float* __restrict__ att_d,
                                               float* __restrict__ a_src,
                                               float* __restrict__ a_dst) {
    constexpr int LDT = 40;
    __shared__ unsigned short As[128 * LDT];
    __shared__ unsigned short Bs[128 * LDT];
    gemm_core<3, 1>(As, Bs, A, KXH, M, Bt, KXH, KXH, C, 512, batch, cw,
                    blockIdx.x * 128, blockIdx.y * 128, att_s, att_d, a_src, a_dst);
}

// ---------------- CSR build ----------------
__global__ void k_cnt(const int* __restrict__ ei, int E, int* cnt) {
    int i = blockIdx.x * 256 + threadIdx.x;
    if (i < E) atomicAdd(&cnt[ei[E + i]], 1);
}
__global__ __launch_bounds__(1024) void k_scan(const int* __restrict__ cnt, int* __restrict__ rowptr,
                                               int* __restrict__ cursor, int n) {
    __shared__ int wsum[16];
    __shared__ int carry;
    int tid = threadIdx.x, lane = tid & 63, wid = tid >> 6;
    if (tid == 0) carry = 0;
    __syncthreads();
    for (int basei = 0; basei < n; basei += 1024) {
        int i = basei + tid;
        int v = (i < n) ? cnt[i] : 0;
        int s = v;
#pragma unroll
        for (int d = 1; d < 64; d <<= 1) {
            int t = __shfl_up(s, (unsigned)d);
            if (lane >= d) s += t;
        }
        if (lane == 63) wsum[wid] = s;
        __syncthreads();
        if (wid == 0 && lane < 16) {
            int ws = wsum[lane]; int t = ws;
#pragma unroll
            for (int d = 1; d < 16; d <<= 1) {
                int u = __shfl_up(t, (unsigned)d);
                if (lane >= d) t += u;
            }
            wsum[lane] = t - ws;  // exclusive wave offsets
        }
        __syncthreads();
        int excl = carry + wsum[wid] + (s - v);
        if (i < n) { rowptr[i] = excl; cursor[i] = excl; }
        __syncthreads();
        if (tid == 1023) carry += wsum[15] + s;
        __syncthreads();
    }
    if (tid == 0) rowptr[n] = carry;
}
__global__ void k_fill(const int* __restrict__ ei, int E, int N, int* cursor, int* csrc) {
    int i = blockIdx.x * 256 + threadIdx.x;
    if (i >= E + N) return;
    int s, d;
    if (i < E) { s = ei[i]; d = ei[E + i]; }
    else { s = i - E; d = s; }
    int slot = atomicAdd(&cursor[d], 1);
    csrc[slot] = s;
}

// ---------------- GAT aggregation: one-pass softmax + 8-deep gather ----------------
__global__ __launch_bounds__(256) void k_agg(const int* __restrict__ rowptr,
                                             const int* __restrict__ csrc,
                                             const float* __restrict__ asrc,
                                             const float* __restrict__ adstv,
                                             const unsigned short* __restrict__ xs,
                                             const float* __restrict__ gbias,
                                             const float* __restrict__ bg,
                                             const float* __restrict__ bb,
                                             const float* __restrict__ bm,
                                             const float* __restrict__ bv,
                                             float* __restrict__ x,
                                             unsigned short* __restrict__ xh, int N) {
    __shared__ float wsh[4][64][4];
    __shared__ int ssh[4][64];
    int tid = threadIdx.x, lane = tid & 63, wid = tid >> 6;
    int n = blockIdx.x * 4 + wid;
    if (n >= N) return;
    int beg = rowptr[n], end = rowptr[n + 1];
    float4 ad = *(const float4*)(adstv + (size_t)n * 4);
    int nch = (end - beg + 63) >> 6;
    // phase A: online per-head max & denom (lane i owns edge beg+i of each chunk)
    float m0 = -1e30f, m1 = -1e30f, m2 = -1e30f, m3 = -1e30f;
    float s0 = 0.f, s1 = 0.f, s2 = 0.f, s3 = 0.f;
    float a0 = -1e30f, a1 = -1e30f, a2 = -1e30f, a3 = -1e30f;  // persisted (single-chunk reuse)
    int sv = 0;
    for (int base = beg; base < end; base += 64) {
        int idx = base + lane;
        float b0 = -1e30f, b1 = -1e30f, b2 = -1e30f, b3 = -1e30f;
        int s = 0;
        if (idx < end) {
            s = csrc[idx];
            float4 t = *(const float4*)(asrc + (size_t)s * 4);
            b0 = t.x + ad.x; b0 = b0 > 0.f ? b0 : 0.2f * b0;
            b1 = t.y + ad.y; b1 = b1 > 0.f ? b1 : 0.2f * b1;
            b2 = t.z + ad.z; b2 = b2 > 0.f ? b2 : 0.2f * b2;
            b3 = t.w + ad.w; b3 = b3 > 0.f ? b3 : 0.2f * b3;
        }
        float c0 = b0, c1 = b1, c2 = b2, c3 = b3;
#pragma unroll
        for (int d = 1; d < 64; d <<= 1) {
            c0 = fmaxf(c0, __shfl_xor(c0, d));
            c1 = fmaxf(c1, __shfl_xor(c1, d));
            c2 = fmaxf(c2, __shfl_xor(c2, d));
            c3 = fmaxf(c3, __shfl_xor(c3, d));
        }
        float nm0 = fmaxf(m0, c0), nm1 = fmaxf(m1, c1), nm2 = fmaxf(m2, c2), nm3 = fmaxf(m3, c3);
        float e0 = (idx < end) ? __expf(b0 - nm0) : 0.f;
        float e1 = (idx < end) ? __expf(b1 - nm1) : 0.f;
        float e2 = (idx < end) ? __expf(b2 - nm2) : 0.f;
        float e3 = (idx < end) ? __expf(b3 - nm3) : 0.f;
#pragma unroll
        for (int d = 1; d < 64; d <<= 1) {
            e0 += __shfl_xor(e0, d); e1 += __shfl_xor(e1, d);
            e2 += __shfl_xor(e2, d); e3 += __shfl_xor(e3, d);
        }
        s0 = s0 * __expf(m0 - nm0) + e0; m0 = nm0;
        s1 = s1 * __expf(m1 - nm1) + e1; m1 = nm1;
        s2 = s2 * __expf(m2 - nm2) + e2; m2 = nm2;
        s3 = s3 * __expf(m3 - nm3) + e3; m3 = nm3;
        a0 = b0; a1 = b1; a2 = b2; a3 = b3; sv = s;
    }
    float i0 = 1.f / fmaxf(s0, 1e-16f), i1 = 1.f / fmaxf(s1, 1e-16f);
    float i2 = 1.f / fmaxf(s2, 1e-16f), i3 = 1.f / fmaxf(s3, 1e-16f);
    // phase B: weighted gather, weights staged in LDS (wave-private), 8-deep clamped unroll
    const int h = lane >> 4, c0i = (lane & 15) * 8;
    float acc[8];
#pragma unroll
    for (int j = 0; j < 8; j++) acc[j] = 0.f;
    for (int base = beg; base < end; base += 64) {
        int s; float w0, w1, w2, w3;
        if (nch == 1) {
            s = sv;
            w0 = __expf(a0 - m0) * i0; w1 = __expf(a1 - m1) * i1;
            w2 = __expf(a2 - m2) * i2; w3 = __expf(a3 - m3) * i3;
        } else {
            int idx = base + lane;
            float b0 = -1e30f, b1 = -1e30f, b2 = -1e30f, b3 = -1e30f;
            s = 0;
            if (idx < end) {
                s = csrc[idx];
                float4 t = *(const float4*)(asrc + (size_t)s * 4);
                b0 = t.x + ad.x; b0 = b0 > 0.f ? b0 : 0.2f * b0;
                b1 = t.y + ad.y; b1 = b1 > 0.f ? b1 : 0.2f * b1;
                b2 = t.z + ad.z; b2 = b2 > 0.f ? b2 : 0.2f * b2;
                b3 = t.w + ad.w; b3 = b3 > 0.f ? b3 : 0.2f * b3;
            }
            w0 = __expf(b0 - m0) * i0; w1 = __expf(b1 - m1) * i1;
            w2 = __expf(b2 - m2) * i2; w3 = __expf(b3 - m3) * i3;
        }
        ssh[wid][lane] = s;
        wsh[wid][lane][0] = w0; wsh[wid][lane][1] = w1;
        wsh[wid][lane][2] = w2; wsh[wid][lane][3] = w3;
        int cnt = min(64, end - base);
        for (int i = 0; i < cnt; i += 8) {
            int sa[8]; float wa[8];
#pragma unroll
            for (int u = 0; u < 8; u++) {
                int ii = min(i + u, cnt - 1);
                sa[u] = ssh[wid][ii];
                wa[u] = (i + u < cnt) ? wsh[wid][ii][h] : 0.f;
            }
            uint4 ra[8];
#pragma unroll
            for (int u = 0; u < 8; u++)
                ra[u] = *(const uint4*)(xs + ((size_t)sa[u] << 9) + (h << 7) + c0i);
#pragma unroll
            for (int u = 0; u < 8; u++) {
                const unsigned short* q = (const unsigned short*)&ra[u];
#pragma unroll
                for (int j = 0; j < 8; j++) acc[j] += wa[u] * bf2f(q[j]);
            }
        }
    }
    // head mean across lanes (h = lane>>4)
#pragma unroll
    for (int j = 0; j < 8; j++) {
        acc[j] += __shfl_xor(acc[j], 16);
        acc[j] += __shfl_xor(acc[j], 32);
    }
    if (lane < 16) {
#pragma unroll
        for (int j = 0; j < 8; j++) {
            int c = c0i + j;
            float t = acc[j] * 0.25f + gbias[c];
            float sc = bg[c] * rsqrtf(bv[c] + 1e-5f);
            float y = (t - bm[c]) * sc + bb[c];
            float ge = 0.5f * y * (1.f + erff(y * 0.70710678118f));
            float xn = x[(size_t)n * 128 + c] + ge;
            x[(size_t)n * 128 + c] = xn;
            xh[(size_t)n * KXH + c] = f2bf(xn);
        }
    }
}

// ---------------- fused pool + final linear ----------------
__global__ __launch_bounds__(256) void k_pool(const float* __restrict__ x,
                                              const int* __restrict__ batch,
                                              const float* __restrict__ W,
                                              const float* __restrict__ bo,
                                              float* __restrict__ out, int N) {
    __shared__ float xg[128];
    __shared__ float tmp[256];
    __shared__ int bounds[2];
    int g = blockIdx.x, tid = threadIdx.x;
    if (tid < 2) {
        int key = g + tid, lo = 0, hi = N;
        while (lo < hi) { int mid = (lo + hi) >> 1; if (batch[mid] < key) lo = mid + 1; else hi = mid; }
        bounds[tid] = lo;
    }
    __syncthreads();
    int s = bounds[0], e = bounds[1];
    int c = tid & 127, rgp = tid >> 7;
    float a = 0.f;
    for (int n = s + rgp; n < e; n += 2) a += x[(size_t)n * 128 + c];
    tmp[tid] = a;
    __syncthreads();
    if (tid < 128) xg[tid] = tmp[tid] + tmp[tid + 128];
    __syncthreads();
    float cntf = (float)(e - s);
    for (int j = tid; j < 1024; j += 256) {
        float o = cntf * bo[j];
        for (int cc = 0; cc < 128; cc++) o += xg[cc] * W[(size_t)cc * 1024 + j];
        out[(size_t)g * 1024 + j] = o;
    }
}

extern "C" void kernel_launch(void* const* d_in, const int* in_sizes, int n_in,
                              void* d_out, int out_size, void* d_ws, size_t ws_size,
                              hipStream_t stream) {
    const int N = in_sizes[0];
    const int E = in_sizes[2] / 2;
    const int NG = in_sizes[5] / CTXD;
    const int* at = (const int*)d_in[0];
    const float* pos = (const float*)d_in[1];
    const int* ei = (const int*)d_in[2];
    const int* batch = (const int*)d_in[4];
    const float* ctx = (const float*)d_in[5];
    const float* embW = (const float*)d_in[6];
    const float* embB = (const float*)d_in[7];
    const float* W1 = (const float*)d_in[8];
    const float* b1 = (const float*)d_in[9];
    const float* rg = (const float*)d_in[10];
    const float* rb = (const float*)d_in[11];
    const float* rm = (const float*)d_in[12];
    const float* rv = (const float*)d_in[13];
    const float* W2 = (const float*)d_in[14];
    const float* b2 = (const float*)d_in[15];
    const float* gatW = (const float*)d_in[16];
    const float* atts = (const float*)d_in[17];
    const float* attd = (const float*)d_in[18];
    const float* gbias = (const float*)d_in[19];
    const float* bg = (const float*)d_in[20];
    const float* bbb = (const float*)d_in[21];
    const float* bm = (const float*)d_in[22];
    const float* bv = (const float*)d_in[23];
    const float* outW = (const float*)d_in[24];
    const float* outb = (const float*)d_in[25];
    float* out = (float*)d_out;

    char* basep = (char*)d_ws;
    size_t off = 0;
    auto alloc = [&](size_t bytes) -> char* {
        char* p = basep + off;
        off = (off + bytes + 255) & ~(size_t)255;
        return p;
    };
    unsigned short* xh = (unsigned short*)alloc((size_t)N * KXH * 2);
    float* x = (float*)alloc((size_t)N * 128 * 4);
    unsigned short* xs = (unsigned short*)alloc((size_t)N * 512 * 2);
    float* a_src = (float*)alloc((size_t)N * 4 * 4);
    float* a_dst = (float*)alloc((size_t)N * 4 * 4);
    int* cnt = (int*)alloc((size_t)N * 4);
    int* rowptr = (int*)alloc((size_t)(N + 1) * 4);
    int* cursor = (int*)alloc((size_t)N * 4);
    int* csrc = (int*)alloc((size_t)(E + N) * 4);
    unsigned short* gatWt = (unsigned short*)alloc((size_t)NLAYERS * 512 * 2176 * 2);
    unsigned short* W1t = (unsigned short*)alloc((size_t)128 * KPAD * 2);
    unsigned short* W2bf = (unsigned short*)alloc((size_t)128 * CTXD * 2);
    unsigned short* cpre = (unsigned short*)alloc((size_t)NG * CTXD * 2);
    unsigned short* Bc = (unsigned short*)alloc((size_t)NLAYERS * 512 * KXH * 2);
    float* cW = (float*)alloc((size_t)NLAYERS * NG * 512 * 4);
    (void)ws_size; (void)n_in; (void)out_size;

    // ---- merged input-only prep ----
    {
        int nbW1t = (128 * KPAD + 255) / 256;
        int nbW2 = (128 * CTXD + 255) / 256;
        int nbCp = (NG * CTXD + 255) / 256;
        int nbCi = (N + 255) / 256;
        int nbEm = (N * 128 + 255) / 256;
        int nbTr = 16 * 68 * 3;
        int e0 = nbW1t, e1 = e0 + nbW2, e2 = e1 + nbCp, e3 = e2 + nbCi, e4 = e3 + nbEm;
        int total = e4 + nbTr;
        k_misc<<<total, 256, 0, stream>>>(W1, W1t, W2, W2bf, ctx, b2, cpre, cnt,
                                          at, embW, embB, x, xh, gatW, gatWt,
                                          N, NG, e0, e1, e2, e3, e4);
    }
    k_cnt<<<(E + 255) / 256, 256, 0, stream>>>(ei, E, cnt);
    // ---- merged RBF + weight-prep GEMMs + Bc copy ----
    {
        int nbRbf = (N + 127) / 128;
        int nbBc = (NLAYERS * 512 * 128 + 255) / 256;
        k_rbfprep<<<nbRbf + 24 + nbBc, 256, 0, stream>>>(pos, W1t, b1, rg, rb, rm, rv, xh,
                                                         gatWt, W2bf, cpre, Bc, cW, N, NG, nbRbf);
    }
    k_scan<<<1, 1024, 0, stream>>>(cnt, rowptr, cursor, N);
    k_fill<<<(E + N + 255) / 256, 256, 0, stream>>>(ei, E, N, cursor, csrc);
    // ---- GAT layers ----
    {
        dim3 g((N + 127) / 128, 4, 1);
        for (int l = 0; l < NLAYERS; l++) {
            k_gemm3<<<g, 256, 0, stream>>>(xh, N, Bc + (size_t)l * 512 * KXH,
                                           xs, batch, cW + (size_t)l * NG * 512,
                                           atts + l * 512, attd + l * 512, a_src, a_dst);
            k_agg<<<(N + 3) / 4, 256, 0, stream>>>(rowptr, csrc, a_src, a_dst, xs,
                                                   gbias + l * 128, bg + l * 128, bbb + l * 128,
                                                   bm + l * 128, bv + l * 128, x, xh, N);
        }
    }
    k_pool<<<NG, 256, 0, stream>>>(x, batch, outW, outb, out, N);
}

// Round 12
// 435.891 us; speedup vs baseline: 1.2031x; 1.0478x over previous
//
#include <hip/hip_runtime.h>
#include <hip/hip_bf16.h>
#include <cstdint>

constexpr int HIDDEN = 128, CTXD = 2048, HEADS = 4, NLAYERS = 3;
constexpr int KRBF = 720, KPAD = 736;  // 736 = 23 * 32
constexpr int KXH = 256;               // concat [x | h] K-dim

typedef __bf16 bf16x8 __attribute__((ext_vector_type(8)));
typedef float f32x4 __attribute__((ext_vector_type(4)));

static __device__ __forceinline__ unsigned short f2bf(float f) {
    union { float f; unsigned u; } v; v.f = f;
    unsigned r = v.u + 0x7fffu + ((v.u >> 16) & 1u);
    return (unsigned short)(r >> 16);
}
static __device__ __forceinline__ float bf2f(unsigned short s) {
    union { unsigned u; float f; } v; v.u = ((unsigned)s) << 16; return v.f;
}

// ================= merged input-only prep (flat-grid partitioned) =================
__global__ __launch_bounds__(256) void k_misc(const float* __restrict__ W1,
                                              unsigned short* __restrict__ W1t,
                                              const float* __restrict__ W2,
                                              unsigned short* __restrict__ W2bf,
                                              const float* __restrict__ ctx,
                                              const float* __restrict__ b2,
                                              unsigned short* __restrict__ cpre,
                                              int* __restrict__ cnt,
                                              const int* __restrict__ at,
                                              const float* __restrict__ embW,
                                              const float* __restrict__ embB,
                                              float* __restrict__ x,
                                              unsigned short* __restrict__ xh,
                                              const float* __restrict__ gatW,
                                              unsigned short* __restrict__ gatWt,
                                              int N, int NG,
                                              int e0, int e1, int e2, int e3, int e4) {
    __shared__ unsigned short t[32][34];
    int b = blockIdx.x, tid = threadIdx.x;
    if (b < e0) {  // W1t
        int i = b * 256 + tid;
        if (i < 128 * KPAD) {
            int c = i / KPAD, k = i % KPAD;
            W1t[i] = (k < KRBF) ? f2bf(W1[(size_t)k * 128 + c]) : (unsigned short)0;
        }
    } else if (b < e1) {  // W2bf
        int i = (b - e0) * 256 + tid;
        if (i < 128 * CTXD) W2bf[i] = f2bf(W2[i]);
    } else if (b < e2) {  // cpre
        int i = (b - e1) * 256 + tid;
        if (i < NG * CTXD) cpre[i] = f2bf(ctx[i] + b2[i % CTXD]);
    } else if (b < e3) {  // cnt init (self-loop)
        int i = (b - e2) * 256 + tid;
        if (i < N) cnt[i] = 1;
    } else if (b < e4) {  // embed
        int i = (b - e3) * 256 + tid;
        if (i < N * HIDDEN) {
            int n = i >> 7, c = i & 127;
            float v = embW[(size_t)at[n] * HIDDEN + c] + embB[c];
            x[i] = v;
            xh[(size_t)n * KXH + c] = f2bf(v);
        }
    } else {  // gatW transpose: f32 [3][2176][512] -> bf16 [3][512][2176]
        int idx = b - e4;
        int bz = idx / (16 * 68);
        int rem = idx % (16 * 68);
        int bx = rem % 16, by = rem / 16;
        int tx = tid & 31, ty = tid >> 5;
        const int R = 2176, C = 512;
        int c0 = bx * 32, r0 = by * 32;
        const float* s = gatW + (size_t)bz * R * C;
        unsigned short* d = gatWt + (size_t)bz * R * C;
        for (int rr = ty; rr < 32; rr += 8) {
            int r = r0 + rr, c = c0 + tx;
            t[rr][tx] = f2bf(s[(size_t)r * C + c]);
        }
        __syncthreads();
        for (int rr = ty; rr < 32; rr += 8) {
            int c = c0 + rr, r = r0 + tx;
            d[(size_t)c * R + r] = t[tx][rr];
        }
    }
}

// ---------------- shared MFMA GEMM core: C[M,N] = A[M,K] @ Bt[N,K]^T ----------------
// MODE 0: bf16 out. MODE 2: f32 out. MODE 3: bf16 out + cw[batch[row]*512+col].
// DOATT=1 (requires MODE 3, 128-col head tile): also emits a_src/a_dst[row][head].
template <int MODE, int DOATT>
__device__ __forceinline__ void gemm_core(unsigned short* As, unsigned short* Bs,
                                          const unsigned short* __restrict__ A, int lda, int M,
                                          const unsigned short* __restrict__ Bt, int ldb, int K,
                                          void* __restrict__ Cout, int ldc,
                                          const int* __restrict__ batch,
                                          const float* __restrict__ cw,
                                          int m0, int n0,
                                          const float* __restrict__ att_s,
                                          const float* __restrict__ att_d,
                                          float* __restrict__ a_src,
                                          float* __restrict__ a_dst) {
    constexpr int LDT = 40;
    const int tid = threadIdx.x;
    const int lane = tid & 63, wid = tid >> 6;
    const int wr = (wid >> 1) * 64, wc = (wid & 1) * 64;
    const int sr = tid >> 1, sk = (tid & 1) * 16;
    f32x4 acc[4][4];
#pragma unroll
    for (int i = 0; i < 4; i++)
#pragma unroll
        for (int j = 0; j < 4; j++)
#pragma unroll
            for (int r = 0; r < 4; r++) acc[i][j][r] = 0.f;
    const int nst = K / 32;
    const int arow = min(m0 + sr, M - 1);
    const unsigned short* ap = A + (size_t)arow * lda + sk;
    const unsigned short* bp = Bt + (size_t)(n0 + sr) * ldb + sk;
    uint4 av0 = *(const uint4*)ap, av1 = *(const uint4*)(ap + 8);
    uint4 bv0 = *(const uint4*)bp, bv1 = *(const uint4*)(bp + 8);
    const int fr = lane & 15, kg = lane >> 4;
    for (int ks = 0; ks < nst; ++ks) {
        __syncthreads();
        *(uint4*)&As[sr * LDT + sk] = av0;
        *(uint4*)&As[sr * LDT + sk + 8] = av1;
        *(uint4*)&Bs[sr * LDT + sk] = bv0;
        *(uint4*)&Bs[sr * LDT + sk + 8] = bv1;
        __syncthreads();
        if (ks + 1 < nst) {  // prefetch next K-step into regs, overlaps with MFMA below
            const unsigned short* ap2 = A + (size_t)arow * lda + (ks + 1) * 32 + sk;
            const unsigned short* bp2 = Bt + (size_t)(n0 + sr) * ldb + (ks + 1) * 32 + sk;
            av0 = *(const uint4*)ap2; av1 = *(const uint4*)(ap2 + 8);
            bv0 = *(const uint4*)bp2; bv1 = *(const uint4*)(bp2 + 8);
        }
        bf16x8 afr[4], bfr[4];
#pragma unroll
        for (int i = 0; i < 4; i++) {
            afr[i] = *reinterpret_cast<const bf16x8*>(&As[(wr + i * 16 + fr) * LDT + kg * 8]);
            bfr[i] = *reinterpret_cast<const bf16x8*>(&Bs[(wc + i * 16 + fr) * LDT + kg * 8]);
        }
#pragma unroll
        for (int i = 0; i < 4; i++)
#pragma unroll
            for (int j = 0; j < 4; j++)
                acc[i][j] = __builtin_amdgcn_mfma_f32_16x16x32_bf16(afr[i], bfr[j], acc[i][j], 0, 0, 0);
    }
    const int rg = lane >> 4;  // C/D: col = lane&15, row = (lane>>4)*4 + reg
    float pssum[4][4], pdsum[4][4];
#pragma unroll
    for (int i = 0; i < 4; i++)
#pragma unroll
        for (int r = 0; r < 4; r++) { pssum[i][r] = 0.f; pdsum[i][r] = 0.f; }
#pragma unroll
    for (int i = 0; i < 4; i++) {
#pragma unroll
        for (int j = 0; j < 4; j++) {
            int col = n0 + wc + j * 16 + fr;
            float asw = 0.f, adw = 0.f;
            if (DOATT) { asw = att_s[col]; adw = att_d[col]; }
#pragma unroll
            for (int r = 0; r < 4; r++) {
                int row = m0 + wr + i * 16 + rg * 4 + r;
                if (row < M) {
                    float vv = acc[i][j][r];
                    if (MODE == 2) {
                        ((float*)Cout)[(size_t)row * ldc + col] = vv;
                    } else if (MODE == 3) {
                        vv += cw[(size_t)batch[row] * 512 + col];
                        ((unsigned short*)Cout)[(size_t)row * ldc + col] = f2bf(vv);
                        if (DOATT) { pssum[i][r] += vv * asw; pdsum[i][r] += vv * adw; }
                    } else {
                        ((unsigned short*)Cout)[(size_t)row * ldc + col] = f2bf(vv);
                    }
                }
            }
        }
    }
    if (DOATT) {
        __syncthreads();  // LDS (As) is dead; reuse for cross-wave att combine
        float* lat = (float*)As;  // [4 waves][64 rows][2]
#pragma unroll
        for (int i = 0; i < 4; i++) {
#pragma unroll
            for (int r = 0; r < 4; r++) {
                float s = pssum[i][r], d = pdsum[i][r];
#pragma unroll
                for (int dd = 1; dd < 16; dd <<= 1) {
                    s += __shfl_xor(s, dd);
                    d += __shfl_xor(d, dd);
                }
                if (fr == 0) {
                    int k = i * 16 + rg * 4 + r;
                    lat[(wid * 64 + k) * 2] = s;
                    lat[(wid * 64 + k) * 2 + 1] = d;
                }
            }
        }
        __syncthreads();
        if ((wid & 1) == 0) {
            int k = lane;
            int row = m0 + (wid >> 1) * 64 + k;
            if (row < M) {
                float s = lat[(wid * 64 + k) * 2] + lat[((wid + 1) * 64 + k) * 2];
                float d = lat[(wid * 64 + k) * 2 + 1] + lat[((wid + 1) * 64 + k) * 2 + 1];
                int head = n0 >> 7;
                a_src[(size_t)row * 4 + head] = s;
                a_dst[(size_t)row * 4 + head] = d;
            }
        }
    }
}

// ============ merged: RBF-MFMA (blocks [0,nbRbf)) + prep GEMMs + Bc copy ============
__global__ __launch_bounds__(256) void k_rbfprep(const float* __restrict__ pos,
                                                 const unsigned short* __restrict__ W1t,
                                                 const float* __restrict__ b1,
                                                 const float* __restrict__ g,
                                                 const float* __restrict__ bb,
                                                 const float* __restrict__ bm,
                                                 const float* __restrict__ bv,
                                                 unsigned short* __restrict__ xh,
                                                 const unsigned short* __restrict__ gatWt,
                                                 const unsigned short* __restrict__ W2bf,
                                                 const unsigned short* __restrict__ cpre,
                                                 unsigned short* __restrict__ Bc,
                                                 float* __restrict__ cW,
                                                 int N, int NG, int nbRbf) {
    constexpr int LDT = 40;
    __shared__ unsigned short As[128 * LDT];
    __shared__ unsigned short Bs[128 * LDT];
    __shared__ float ps[128 * 3];
    const int bid = blockIdx.x;
    const int tid = threadIdx.x;
    if (bid >= nbRbf) {
        int idx = bid - nbRbf;
        if (idx < 12) {  // Bc[l][:,128:256] = Wc[l]^T @ W2^T
            int z = idx >> 2, mt = idx & 3;
            gemm_core<0, 0>(As, Bs, gatWt + (size_t)z * 512 * 2176 + 128, 2176, 512,
                            W2bf, CTXD, CTXD, Bc + (size_t)z * 512 * KXH + 128, KXH,
                            nullptr, nullptr, mt * 128, 0, nullptr, nullptr, nullptr, nullptr);
        } else if (idx < 24) {  // cW[l] = cpre @ Wc[l]
            int z = (idx - 12) >> 2, nt = (idx - 12) & 3;
            gemm_core<2, 0>(As, Bs, cpre, CTXD, NG, gatWt + (size_t)z * 512 * 2176 + 128, 2176,
                            CTXD, cW + (size_t)z * NG * 512, 512, nullptr, nullptr, 0, nt * 128,
                            nullptr, nullptr, nullptr, nullptr);
        } else {  // Bc[l][o][0:128] = gatWt[l][o][0:128]
            int i = (idx - 24) * 256 + tid;
            if (i < NLAYERS * 512 * 128) {
                int lo = i >> 7, k = i & 127;
                Bc[(size_t)lo * KXH + k] = gatWt[(size_t)lo * 2176 + k];
            }
        }
        return;
    }
    // ---- RBF + Linear(720->128) via MFMA + BN + ReLU -> xh[:,128:256] ----
    const int lane = tid & 63, wid = tid >> 6;
    const int nb = bid * 128;
    for (int i = tid; i < 384; i += 256) {
        int n = nb + i / 3;
        ps[i] = (n < N) ? pos[(size_t)n * 3 + (i % 3)] : 1.0e9f;  // pad rows -> rbf = 0
    }
    __syncthreads();
    const int sr = tid >> 1, sk = (tid & 1) * 16;
    const int wr = (wid >> 1) * 64, wc = (wid & 1) * 64;
    const int fr = lane & 15, kg = lane >> 4;
    f32x4 acc[4][4];
#pragma unroll
    for (int i = 0; i < 4; i++)
#pragma unroll
        for (int j = 0; j < 4; j++)
#pragma unroll
            for (int r = 0; r < 4; r++) acc[i][j][r] = 0.f;
    const float p0 = ps[sr * 3], p1 = ps[sr * 3 + 1], p2 = ps[sr * 3 + 2];
    const unsigned short* bp = W1t + (size_t)sr * KPAD + sk;
    uint4 bv0 = *(const uint4*)bp, bv1 = *(const uint4*)(bp + 8);
    constexpr int NST = KPAD / 32;
    for (int ks = 0; ks < NST; ++ks) {
        unsigned short av[16];
#pragma unroll
        for (int j = 0; j < 16; j++) {
            int kglob = ks * 32 + sk + j;
            float v = 0.f;
            if (kglob < KRBF) {
                int d = kglob / 240, bin = kglob % 240;
                float mu = -30.f + (60.f / 239.f) * (float)bin;
                float p = (d == 0) ? p0 : ((d == 1) ? p1 : p2);
                float df = p - mu;
                v = __expf(-0.5f * df * df);
            }
            av[j] = f2bf(v);
        }
        __syncthreads();
        *(uint4*)&As[sr * LDT + sk] = *(const uint4*)&av[0];
        *(uint4*)&As[sr * LDT + sk + 8] = *(const uint4*)&av[8];
        *(uint4*)&Bs[sr * LDT + sk] = bv0;
        *(uint4*)&Bs[sr * LDT + sk + 8] = bv1;
        __syncthreads();
        if (ks + 1 < NST) {
            const unsigned short* bp2 = W1t + (size_t)sr * KPAD + (ks + 1) * 32 + sk;
            bv0 = *(const uint4*)bp2;
            bv1 = *(const uint4*)(bp2 + 8);
        }
        bf16x8 afr[4], bfr[4];
#pragma unroll
        for (int i = 0; i < 4; i++) {
            afr[i] = *reinterpret_cast<const bf16x8*>(&As[(wr + i * 16 + fr) * LDT + kg * 8]);
            bfr[i] = *reinterpret_cast<const bf16x8*>(&Bs[(wc + i * 16 + fr) * LDT + kg * 8]);
        }
#pragma unroll
        for (int i = 0; i < 4; i++)
#pragma unroll
            for (int j = 0; j < 4; j++)
                acc[i][j] = __builtin_amdgcn_mfma_f32_16x16x32_bf16(afr[i], bfr[j], acc[i][j], 0, 0, 0);
    }
    const int rg = lane >> 4;
#pragma unroll
    for (int i = 0; i < 4; i++) {
#pragma unroll
        for (int j = 0; j < 4; j++) {
            int col = wc + j * 16 + fr;
            float sc = g[col] * rsqrtf(bv[col] + 1e-5f);
            float sh = bb[col] - bm[col] * sc;
            float bc = b1[col];
#pragma unroll
            for (int r = 0; r < 4; r++) {
                int row = nb + wr + i * 16 + rg * 4 + r;
                if (row < N) {
                    float y = (acc[i][j][r] + bc) * sc + sh;
                    y = fmaxf(y, 0.f);
                    xh[(size_t)row * KXH + 128 + col] = f2bf(y);
                }
            }
        }
    }
}

// GAT per-layer node GEMM (MODE 3 + fused attention logits)
__global__ __launch_bounds__(256) void k_gemm3(const unsigned short* __restrict__ A, int M,
                                               const unsigned short* __restrict__ Bt,
                                               unsigned short* __restrict__ C,
                                               const int* __restrict__ batch,
                                               const float* __restrict__ cw,
                                               const float* __restrict__ att_s,
                                               const float* __restrict__ att_d,
                                               float* __restrict__ a_src,
                                               float* __restrict__ a_dst) {
    constexpr int LDT = 40;
    __shared__ unsigned short As[128 * LDT];
    __shared__ unsigned short Bs[128 * LDT];
    gemm_core<3, 1>(As, Bs, A, KXH, M, Bt, KXH, KXH, C, 512, batch, cw,
                    blockIdx.x * 128, blockIdx.y * 128, att_s, att_d, a_src, a_dst);
}

// ---------------- CSR build ----------------
__global__ void k_cnt(const int* __restrict__ ei, int E, int* cnt) {
    int i = blockIdx.x * 256 + threadIdx.x;
    if (i < E) atomicAdd(&cnt[ei[E + i]], 1);
}
__global__ __launch_bounds__(1024) void k_scan(const int* __restrict__ cnt, int* __restrict__ rowptr,
                                               int* __restrict__ cursor, int n) {
    __shared__ int wsum[16];
    __shared__ int carry;
    int tid = threadIdx.x, lane = tid & 63, wid = tid >> 6;
    if (tid == 0) carry = 0;
    __syncthreads();
    for (int basei = 0; basei < n; basei += 1024) {
        int i = basei + tid;
        int v = (i < n) ? cnt[i] : 0;
        int s = v;
#pragma unroll
        for (int d = 1; d < 64; d <<= 1) {
            int t = __shfl_up(s, (unsigned)d);
            if (lane >= d) s += t;
        }
        if (lane == 63) wsum[wid] = s;
        __syncthreads();
        if (wid == 0 && lane < 16) {
            int ws = wsum[lane]; int t = ws;
#pragma unroll
            for (int d = 1; d < 16; d <<= 1) {
                int u = __shfl_up(t, (unsigned)d);
                if (lane >= d) t += u;
            }
            wsum[lane] = t - ws;  // exclusive wave offsets
        }
        __syncthreads();
        int excl = carry + wsum[wid] + (s - v);
        if (i < n) { rowptr[i] = excl; cursor[i] = excl; }
        __syncthreads();
        if (tid == 1023) carry += wsum[15] + s;
        __syncthreads();
    }
    if (tid == 0) rowptr[n] = carry;
}
__global__ void k_fill(const int* __restrict__ ei, int E, int N, int* cursor, int* csrc) {
    int i = blockIdx.x * 256 + threadIdx.x;
    if (i >= E + N) return;
    int s, d;
    if (i < E) { s = ei[i]; d = ei[E + i]; }
    else { s = i - E; d = s; }
    int slot = atomicAdd(&cursor[d], 1);
    csrc[slot] = s;
}

// ---------------- GAT aggregation: one-pass softmax + LDS-staged 2-deep gather ----------------
__global__ __launch_bounds__(256) void k_agg(const int* __restrict__ rowptr,
                                             const int* __restrict__ csrc,
                                             const float* __restrict__ asrc,
                                             const float* __restrict__ adstv,
                                             const unsigned short* __restrict__ xs,
                                             const float* __restrict__ gbias,
                                             const float* __restrict__ bg,
                                             const float* __restrict__ bb,
                                             const float* __restrict__ bm,
                                             const float* __restrict__ bv,
                                             float* __restrict__ x,
                                             unsigned short* __restrict__ xh, int N) {
    __shared__ float wsh[4][64][4];
    __shared__ int ssh[4][64];
    int tid = threadIdx.x, lane = tid & 63, wid = tid >> 6;
    int n = blockIdx.x * 4 + wid;
    if (n >= N) return;
    int beg = rowptr[n], end = rowptr[n + 1];
    float4 ad = *(const float4*)(adstv + (size_t)n * 4);
    int nch = (end - beg + 63) >> 6;
    // phase A: online per-head max & denom (lane i owns edge beg+i of each chunk)
    float m0 = -1e30f, m1 = -1e30f, m2 = -1e30f, m3 = -1e30f;
    float s0 = 0.f, s1 = 0.f, s2 = 0.f, s3 = 0.f;
    float a0 = -1e30f, a1 = -1e30f, a2 = -1e30f, a3 = -1e30f;  // persisted (single-chunk reuse)
    int sv = 0;
    for (int base = beg; base < end; base += 64) {
        int idx = base + lane;
        float b0 = -1e30f, b1 = -1e30f, b2 = -1e30f, b3 = -1e30f;
        int s = 0;
        if (idx < end) {
            s = csrc[idx];
            float4 t = *(const float4*)(asrc + (size_t)s * 4);
            b0 = t.x + ad.x; b0 = b0 > 0.f ? b0 : 0.2f * b0;
            b1 = t.y + ad.y; b1 = b1 > 0.f ? b1 : 0.2f * b1;
            b2 = t.z + ad.z; b2 = b2 > 0.f ? b2 : 0.2f * b2;
            b3 = t.w + ad.w; b3 = b3 > 0.f ? b3 : 0.2f * b3;
        }
        float c0 = b0, c1 = b1, c2 = b2, c3 = b3;
#pragma unroll
        for (int d = 1; d < 64; d <<= 1) {
            c0 = fmaxf(c0, __shfl_xor(c0, d));
            c1 = fmaxf(c1, __shfl_xor(c1, d));
            c2 = fmaxf(c2, __shfl_xor(c2, d));
            c3 = fmaxf(c3, __shfl_xor(c3, d));
        }
        float nm0 = fmaxf(m0, c0), nm1 = fmaxf(m1, c1), nm2 = fmaxf(m2, c2), nm3 = fmaxf(m3, c3);
        float e0 = (idx < end) ? __expf(b0 - nm0) : 0.f;
        float e1 = (idx < end) ? __expf(b1 - nm1) : 0.f;
        float e2 = (idx < end) ? __expf(b2 - nm2) : 0.f;
        float e3 = (idx < end) ? __expf(b3 - nm3) : 0.f;
#pragma unroll
        for (int d = 1; d < 64; d <<= 1) {
            e0 += __shfl_xor(e0, d); e1 += __shfl_xor(e1, d);
            e2 += __shfl_xor(e2, d); e3 += __shfl_xor(e3, d);
        }
        s0 = s0 * __expf(m0 - nm0) + e0; m0 = nm0;
        s1 = s1 * __expf(m1 - nm1) + e1; m1 = nm1;
        s2 = s2 * __expf(m2 - nm2) + e2; m2 = nm2;
        s3 = s3 * __expf(m3 - nm3) + e3; m3 = nm3;
        a0 = b0; a1 = b1; a2 = b2; a3 = b3; sv = s;
    }
    float i0 = 1.f / fmaxf(s0, 1e-16f), i1 = 1.f / fmaxf(s1, 1e-16f);
    float i2 = 1.f / fmaxf(s2, 1e-16f), i3 = 1.f / fmaxf(s3, 1e-16f);
    // phase B: weighted gather, per-edge weights staged in LDS (wave-private), 2-deep
    const int h = lane >> 4, c0i = (lane & 15) * 8;
    float acc[8];
#pragma unroll
    for (int j = 0; j < 8; j++) acc[j] = 0.f;
    for (int base = beg; base < end; base += 64) {
        int s; float w0, w1, w2, w3;
        if (nch == 1) {
            s = sv;
            w0 = __expf(a0 - m0) * i0; w1 = __expf(a1 - m1) * i1;
            w2 = __expf(a2 - m2) * i2; w3 = __expf(a3 - m3) * i3;
        } else {
            int idx = base + lane;
            float b0 = -1e30f, b1 = -1e30f, b2 = -1e30f, b3 = -1e30f;
            s = 0;
            if (idx < end) {
                s = csrc[idx];
                float4 t = *(const float4*)(asrc + (size_t)s * 4);
                b0 = t.x + ad.x; b0 = b0 > 0.f ? b0 : 0.2f * b0;
                b1 = t.y + ad.y; b1 = b1 > 0.f ? b1 : 0.2f * b1;
                b2 = t.z + ad.z; b2 = b2 > 0.f ? b2 : 0.2f * b2;
                b3 = t.w + ad.w; b3 = b3 > 0.f ? b3 : 0.2f * b3;
            }
            w0 = __expf(b0 - m0) * i0; w1 = __expf(b1 - m1) * i1;
            w2 = __expf(b2 - m2) * i2; w3 = __expf(b3 - m3) * i3;
        }
        ssh[wid][lane] = s;
        wsh[wid][lane][0] = w0; wsh[wid][lane][1] = w1;
        wsh[wid][lane][2] = w2; wsh[wid][lane][3] = w3;
        int cnt = min(64, end - base);
        int i = 0;
        for (; i + 2 <= cnt; i += 2) {
            int sa = ssh[wid][i], sb = ssh[wid][i + 1];
            float wa = wsh[wid][i][h], wb = wsh[wid][i + 1][h];
            uint4 ra = *(const uint4*)(xs + ((size_t)sa << 9) + (h << 7) + c0i);
            uint4 rb = *(const uint4*)(xs + ((size_t)sb << 9) + (h << 7) + c0i);
            const unsigned short* qa = (const unsigned short*)&ra;
            const unsigned short* qb = (const unsigned short*)&rb;
#pragma unroll
            for (int j = 0; j < 8; j++) acc[j] += wa * bf2f(qa[j]);
#pragma unroll
            for (int j = 0; j < 8; j++) acc[j] += wb * bf2f(qb[j]);
        }
        if (i < cnt) {
            int sa = ssh[wid][i];
            float wa = wsh[wid][i][h];
            uint4 ra = *(const uint4*)(xs + ((size_t)sa << 9) + (h << 7) + c0i);
            const unsigned short* qa = (const unsigned short*)&ra;
#pragma unroll
            for (int j = 0; j < 8; j++) acc[j] += wa * bf2f(qa[j]);
        }
    }
    // head mean across lanes (h = lane>>4)
#pragma unroll
    for (int j = 0; j < 8; j++) {
        acc[j] += __shfl_xor(acc[j], 16);
        acc[j] += __shfl_xor(acc[j], 32);
    }
    if (lane < 16) {
#pragma unroll
        for (int j = 0; j < 8; j++) {
            int c = c0i + j;
            float t = acc[j] * 0.25f + gbias[c];
            float sc = bg[c] * rsqrtf(bv[c] + 1e-5f);
            float y = (t - bm[c]) * sc + bb[c];
            float ge = 0.5f * y * (1.f + erff(y * 0.70710678118f));
            float xn = x[(size_t)n * 128 + c] + ge;
            x[(size_t)n * 128 + c] = xn;
            xh[(size_t)n * KXH + c] = f2bf(xn);
        }
    }
}

// ---------------- fused pool + final linear ----------------
__global__ __launch_bounds__(256) void k_pool(const float* __restrict__ x,
                                              const int* __restrict__ batch,
                                              const float* __restrict__ W,
                                              const float* __restrict__ bo,
                                              float* __restrict__ out, int N) {
    __shared__ float xg[128];
    __shared__ float tmp[256];
    __shared__ int bounds[2];
    int g = blockIdx.x, tid = threadIdx.x;
    if (tid < 2) {
        int key = g + tid, lo = 0, hi = N;
        while (lo < hi) { int mid = (lo + hi) >> 1; if (batch[mid] < key) lo = mid + 1; else hi = mid; }
        bounds[tid] = lo;
    }
    __syncthreads();
    int s = bounds[0], e = bounds[1];
    int c = tid & 127, rgp = tid >> 7;
    float a = 0.f;
    for (int n = s + rgp; n < e; n += 2) a += x[(size_t)n * 128 + c];
    tmp[tid] = a;
    __syncthreads();
    if (tid < 128) xg[tid] = tmp[tid] + tmp[tid + 128];
    __syncthreads();
    float cntf = (float)(e - s);
    for (int j = tid; j < 1024; j += 256) {
        float o = cntf * bo[j];
        for (int cc = 0; cc < 128; cc++) o += xg[cc] * W[(size_t)cc * 1024 + j];
        out[(size_t)g * 1024 + j] = o;
    }
}

extern "C" void kernel_launch(void* const* d_in, const int* in_sizes, int n_in,
                              void* d_out, int out_size, void* d_ws, size_t ws_size,
                              hipStream_t stream) {
    const int N = in_sizes[0];
    const int E = in_sizes[2] / 2;
    const int NG = in_sizes[5] / CTXD;
    const int* at = (const int*)d_in[0];
    const float* pos = (const float*)d_in[1];
    const int* ei = (const int*)d_in[2];
    const int* batch = (const int*)d_in[4];
    const float* ctx = (const float*)d_in[5];
    const float* embW = (const float*)d_in[6];
    const float* embB = (const float*)d_in[7];
    const float* W1 = (const float*)d_in[8];
    const float* b1 = (const float*)d_in[9];
    const float* rg = (const float*)d_in[10];
    const float* rb = (const float*)d_in[11];
    const float* rm = (const float*)d_in[12];
    const float* rv = (const float*)d_in[13];
    const float* W2 = (const float*)d_in[14];
    const float* b2 = (const float*)d_in[15];
    const float* gatW = (const float*)d_in[16];
    const float* atts = (const float*)d_in[17];
    const float* attd = (const float*)d_in[18];
    const float* gbias = (const float*)d_in[19];
    const float* bg = (const float*)d_in[20];
    const float* bbb = (const float*)d_in[21];
    const float* bm = (const float*)d_in[22];
    const float* bv = (const float*)d_in[23];
    const float* outW = (const float*)d_in[24];
    const float* outb = (const float*)d_in[25];
    float* out = (float*)d_out;

    char* basep = (char*)d_ws;
    size_t off = 0;
    auto alloc = [&](size_t bytes) -> char* {
        char* p = basep + off;
        off = (off + bytes + 255) & ~(size_t)255;
        return p;
    };
    unsigned short* xh = (unsigned short*)alloc((size_t)N * KXH * 2);
    float* x = (float*)alloc((size_t)N * 128 * 4);
    unsigned short* xs = (unsigned short*)alloc((size_t)N * 512 * 2);
    float* a_src = (float*)alloc((size_t)N * 4 * 4);
    float* a_dst = (float*)alloc((size_t)N * 4 * 4);
    int* cnt = (int*)alloc((size_t)N * 4);
    int* rowptr = (int*)alloc((size_t)(N + 1) * 4);
    int* cursor = (int*)alloc((size_t)N * 4);
    int* csrc = (int*)alloc((size_t)(E + N) * 4);
    unsigned short* gatWt = (unsigned short*)alloc((size_t)NLAYERS * 512 * 2176 * 2);
    unsigned short* W1t = (unsigned short*)alloc((size_t)128 * KPAD * 2);
    unsigned short* W2bf = (unsigned short*)alloc((size_t)128 * CTXD * 2);
    unsigned short* cpre = (unsigned short*)alloc((size_t)NG * CTXD * 2);
    unsigned short* Bc = (unsigned short*)alloc((size_t)NLAYERS * 512 * KXH * 2);
    float* cW = (float*)alloc((size_t)NLAYERS * NG * 512 * 4);
    (void)ws_size; (void)n_in; (void)out_size;

    // ---- merged input-only prep ----
    {
        int nbW1t = (128 * KPAD + 255) / 256;
        int nbW2 = (128 * CTXD + 255) / 256;
        int nbCp = (NG * CTXD + 255) / 256;
        int nbCi = (N + 255) / 256;
        int nbEm = (N * 128 + 255) / 256;
        int nbTr = 16 * 68 * 3;
        int e0 = nbW1t, e1 = e0 + nbW2, e2 = e1 + nbCp, e3 = e2 + nbCi, e4 = e3 + nbEm;
        int total = e4 + nbTr;
        k_misc<<<total, 256, 0, stream>>>(W1, W1t, W2, W2bf, ctx, b2, cpre, cnt,
                                          at, embW, embB, x, xh, gatW, gatWt,
                                          N, NG, e0, e1, e2, e3, e4);
    }
    k_cnt<<<(E + 255) / 256, 256, 0, stream>>>(ei, E, cnt);
    // ---- merged RBF + weight-prep GEMMs + Bc copy ----
    {
        int nbRbf = (N + 127) / 128;
        int nbBc = (NLAYERS * 512 * 128 + 255) / 256;
        k_rbfprep<<<nbRbf + 24 + nbBc, 256, 0, stream>>>(pos, W1t, b1, rg, rb, rm, rv, xh,
                                                         gatWt, W2bf, cpre, Bc, cW, N, NG, nbRbf);
    }
    k_scan<<<1, 1024, 0, stream>>>(cnt, rowptr, cursor, N);
    k_fill<<<(E + N + 255) / 256, 256, 0, stream>>>(ei, E, N, cursor, csrc);
    // ---- GAT layers ----
    {
        dim3 g((N + 127) / 128, 4, 1);
        for (int l = 0; l < NLAYERS; l++) {
            k_gemm3<<<g, 256, 0, stream>>>(xh, N, Bc + (size_t)l * 512 * KXH,
                                           xs, batch, cW + (size_t)l * NG * 512,
                                           atts + l * 512, attd + l * 512, a_src, a_dst);
            k_agg<<<(N + 3) / 4, 256, 0, stream>>>(rowptr, csrc, a_src, a_dst, xs,
                                                   gbias + l * 128, bg + l * 128, bbb + l * 128,
                                                   bm + l * 128, bv + l * 128, x, xh, N);
        }
    }
    k_pool<<<NG, 256, 0, stream>>>(x, batch, outW, outb, out, N);
}

// Round 13
// 434.118 us; speedup vs baseline: 1.2080x; 1.0041x over previous
//
#include <hip/hip_runtime.h>
#include <hip/hip_bf16.h>
#include <cstdint>

constexpr int HIDDEN = 128, CTXD = 2048, HEADS = 4, NLAYERS = 3;
constexpr int KRBF = 720, KPAD = 736;  // 736 = 23 * 32
constexpr int KXH = 256;               // concat [x | h] K-dim

typedef __bf16 bf16x8 __attribute__((ext_vector_type(8)));
typedef float f32x4 __attribute__((ext_vector_type(4)));

static __device__ __forceinline__ unsigned short f2bf(float f) {
    union { float f; unsigned u; } v; v.f = f;
    unsigned r = v.u + 0x7fffu + ((v.u >> 16) & 1u);
    return (unsigned short)(r >> 16);
}
static __device__ __forceinline__ float bf2f(unsigned short s) {
    union { unsigned u; float f; } v; v.u = ((unsigned)s) << 16; return v.f;
}

// ================= merged input-only prep (flat-grid partitioned) =================
__global__ __launch_bounds__(256) void k_misc(const float* __restrict__ W1,
                                              unsigned short* __restrict__ W1t,
                                              const float* __restrict__ W2,
                                              unsigned short* __restrict__ W2bf,
                                              const float* __restrict__ ctx,
                                              const float* __restrict__ b2,
                                              unsigned short* __restrict__ cpre,
                                              int* __restrict__ cnt,
                                              const int* __restrict__ at,
                                              const float* __restrict__ embW,
                                              const float* __restrict__ embB,
                                              float* __restrict__ x,
                                              unsigned short* __restrict__ xh,
                                              const float* __restrict__ gatW,
                                              unsigned short* __restrict__ gatWt,
                                              int N, int NG,
                                              int e0, int e1, int e2, int e3, int e4) {
    __shared__ unsigned short t[32][34];
    int b = blockIdx.x, tid = threadIdx.x;
    if (b < e0) {  // W1t
        int i = b * 256 + tid;
        if (i < 128 * KPAD) {
            int c = i / KPAD, k = i % KPAD;
            W1t[i] = (k < KRBF) ? f2bf(W1[(size_t)k * 128 + c]) : (unsigned short)0;
        }
    } else if (b < e1) {  // W2bf
        int i = (b - e0) * 256 + tid;
        if (i < 128 * CTXD) W2bf[i] = f2bf(W2[i]);
    } else if (b < e2) {  // cpre
        int i = (b - e1) * 256 + tid;
        if (i < NG * CTXD) cpre[i] = f2bf(ctx[i] + b2[i % CTXD]);
    } else if (b < e3) {  // cnt init (self-loop)
        int i = (b - e2) * 256 + tid;
        if (i < N) cnt[i] = 1;
    } else if (b < e4) {  // embed
        int i = (b - e3) * 256 + tid;
        if (i < N * HIDDEN) {
            int n = i >> 7, c = i & 127;
            float v = embW[(size_t)at[n] * HIDDEN + c] + embB[c];
            x[i] = v;
            xh[(size_t)n * KXH + c] = f2bf(v);
        }
    } else {  // gatW transpose: f32 [3][2176][512] -> bf16 [3][512][2176]
        int idx = b - e4;
        int bz = idx / (16 * 68);
        int rem = idx % (16 * 68);
        int bx = rem % 16, by = rem / 16;
        int tx = tid & 31, ty = tid >> 5;
        const int R = 2176, C = 512;
        int c0 = bx * 32, r0 = by * 32;
        const float* s = gatW + (size_t)bz * R * C;
        unsigned short* d = gatWt + (size_t)bz * R * C;
        for (int rr = ty; rr < 32; rr += 8) {
            int r = r0 + rr, c = c0 + tx;
            t[rr][tx] = f2bf(s[(size_t)r * C + c]);
        }
        __syncthreads();
        for (int rr = ty; rr < 32; rr += 8) {
            int c = c0 + rr, r = r0 + tx;
            d[(size_t)c * R + r] = t[tx][rr];
        }
    }
}

// ---------------- shared MFMA GEMM core (prep GEMMs): C[M,N] = A[M,K] @ Bt[N,K]^T --------
// MODE 0: bf16 out. MODE 2: f32 out.
template <int MODE>
__device__ __forceinline__ void gemm_core(unsigned short* As, unsigned short* Bs,
                                          const unsigned short* __restrict__ A, int lda, int M,
                                          const unsigned short* __restrict__ Bt, int ldb, int K,
                                          void* __restrict__ Cout, int ldc,
                                          int m0, int n0) {
    constexpr int LDT = 40;
    const int tid = threadIdx.x;
    const int lane = tid & 63, wid = tid >> 6;
    const int wr = (wid >> 1) * 64, wc = (wid & 1) * 64;
    const int sr = tid >> 1, sk = (tid & 1) * 16;
    f32x4 acc[4][4];
#pragma unroll
    for (int i = 0; i < 4; i++)
#pragma unroll
        for (int j = 0; j < 4; j++)
#pragma unroll
            for (int r = 0; r < 4; r++) acc[i][j][r] = 0.f;
    const int nst = K / 32;
    const int arow = min(m0 + sr, M - 1);
    const unsigned short* ap = A + (size_t)arow * lda + sk;
    const unsigned short* bp = Bt + (size_t)(n0 + sr) * ldb + sk;
    uint4 av0 = *(const uint4*)ap, av1 = *(const uint4*)(ap + 8);
    uint4 bv0 = *(const uint4*)bp, bv1 = *(const uint4*)(bp + 8);
    const int fr = lane & 15, kg = lane >> 4;
    for (int ks = 0; ks < nst; ++ks) {
        __syncthreads();
        *(uint4*)&As[sr * LDT + sk] = av0;
        *(uint4*)&As[sr * LDT + sk + 8] = av1;
        *(uint4*)&Bs[sr * LDT + sk] = bv0;
        *(uint4*)&Bs[sr * LDT + sk + 8] = bv1;
        __syncthreads();
        if (ks + 1 < nst) {
            const unsigned short* ap2 = A + (size_t)arow * lda + (ks + 1) * 32 + sk;
            const unsigned short* bp2 = Bt + (size_t)(n0 + sr) * ldb + (ks + 1) * 32 + sk;
            av0 = *(const uint4*)ap2; av1 = *(const uint4*)(ap2 + 8);
            bv0 = *(const uint4*)bp2; bv1 = *(const uint4*)(bp2 + 8);
        }
        bf16x8 afr[4], bfr[4];
#pragma unroll
        for (int i = 0; i < 4; i++) {
            afr[i] = *reinterpret_cast<const bf16x8*>(&As[(wr + i * 16 + fr) * LDT + kg * 8]);
            bfr[i] = *reinterpret_cast<const bf16x8*>(&Bs[(wc + i * 16 + fr) * LDT + kg * 8]);
        }
#pragma unroll
        for (int i = 0; i < 4; i++)
#pragma unroll
            for (int j = 0; j < 4; j++)
                acc[i][j] = __builtin_amdgcn_mfma_f32_16x16x32_bf16(afr[i], bfr[j], acc[i][j], 0, 0, 0);
    }
    const int rg = lane >> 4;  // C/D: col = lane&15, row = (lane>>4)*4 + reg
#pragma unroll
    for (int i = 0; i < 4; i++) {
#pragma unroll
        for (int j = 0; j < 4; j++) {
            int col = n0 + wc + j * 16 + fr;
#pragma unroll
            for (int r = 0; r < 4; r++) {
                int row = m0 + wr + i * 16 + rg * 4 + r;
                if (row < M) {
                    float vv = acc[i][j][r];
                    if (MODE == 2) {
                        ((float*)Cout)[(size_t)row * ldc + col] = vv;
                    } else {
                        ((unsigned short*)Cout)[(size_t)row * ldc + col] = f2bf(vv);
                    }
                }
            }
        }
    }
}

// ============ merged: RBF-MFMA (blocks [0,nbRbf)) + prep GEMMs + Bc copy ============
__global__ __launch_bounds__(256) void k_rbfprep(const float* __restrict__ pos,
                                                 const unsigned short* __restrict__ W1t,
                                                 const float* __restrict__ b1,
                                                 const float* __restrict__ g,
                                                 const float* __restrict__ bb,
                                                 const float* __restrict__ bm,
                                                 const float* __restrict__ bv,
                                                 unsigned short* __restrict__ xh,
                                                 const unsigned short* __restrict__ gatWt,
                                                 const unsigned short* __restrict__ W2bf,
                                                 const unsigned short* __restrict__ cpre,
                                                 unsigned short* __restrict__ Bc,
                                                 float* __restrict__ cW,
                                                 int N, int NG, int nbRbf) {
    constexpr int LDT = 40;
    __shared__ unsigned short As[128 * LDT];
    __shared__ unsigned short Bs[128 * LDT];
    __shared__ float ps[128 * 3];
    const int bid = blockIdx.x;
    const int tid = threadIdx.x;
    if (bid >= nbRbf) {
        int idx = bid - nbRbf;
        if (idx < 12) {  // Bc[l][:,128:256] = Wc[l]^T @ W2^T
            int z = idx >> 2, mt = idx & 3;
            gemm_core<0>(As, Bs, gatWt + (size_t)z * 512 * 2176 + 128, 2176, 512,
                         W2bf, CTXD, CTXD, Bc + (size_t)z * 512 * KXH + 128, KXH,
                         mt * 128, 0);
        } else if (idx < 24) {  // cW[l] = cpre @ Wc[l]
            int z = (idx - 12) >> 2, nt = (idx - 12) & 3;
            gemm_core<2>(As, Bs, cpre, CTXD, NG, gatWt + (size_t)z * 512 * 2176 + 128, 2176,
                         CTXD, cW + (size_t)z * NG * 512, 512, 0, nt * 128);
        } else {  // Bc[l][o][0:128] = gatWt[l][o][0:128]
            int i = (idx - 24) * 256 + tid;
            if (i < NLAYERS * 512 * 128) {
                int lo = i >> 7, k = i & 127;
                Bc[(size_t)lo * KXH + k] = gatWt[(size_t)lo * 2176 + k];
            }
        }
        return;
    }
    // ---- RBF + Linear(720->128) via MFMA + BN + ReLU -> xh[:,128:256] ----
    const int lane = tid & 63, wid = tid >> 6;
    const int nb = bid * 128;
    for (int i = tid; i < 384; i += 256) {
        int n = nb + i / 3;
        ps[i] = (n < N) ? pos[(size_t)n * 3 + (i % 3)] : 1.0e9f;  // pad rows -> rbf = 0
    }
    __syncthreads();
    const int sr = tid >> 1, sk = (tid & 1) * 16;
    const int wr = (wid >> 1) * 64, wc = (wid & 1) * 64;
    const int fr = lane & 15, kg = lane >> 4;
    f32x4 acc[4][4];
#pragma unroll
    for (int i = 0; i < 4; i++)
#pragma unroll
        for (int j = 0; j < 4; j++)
#pragma unroll
            for (int r = 0; r < 4; r++) acc[i][j][r] = 0.f;
    const float p0 = ps[sr * 3], p1 = ps[sr * 3 + 1], p2 = ps[sr * 3 + 2];
    const unsigned short* bp = W1t + (size_t)sr * KPAD + sk;
    uint4 bv0 = *(const uint4*)bp, bv1 = *(const uint4*)(bp + 8);
    constexpr int NST = KPAD / 32;
    for (int ks = 0; ks < NST; ++ks) {
        unsigned short av[16];
#pragma unroll
        for (int j = 0; j < 16; j++) {
            int kglob = ks * 32 + sk + j;
            float v = 0.f;
            if (kglob < KRBF) {
                int d = kglob / 240, bin = kglob % 240;
                float mu = -30.f + (60.f / 239.f) * (float)bin;
                float p = (d == 0) ? p0 : ((d == 1) ? p1 : p2);
                float df = p - mu;
                v = __expf(-0.5f * df * df);
            }
            av[j] = f2bf(v);
        }
        __syncthreads();
        *(uint4*)&As[sr * LDT + sk] = *(const uint4*)&av[0];
        *(uint4*)&As[sr * LDT + sk + 8] = *(const uint4*)&av[8];
        *(uint4*)&Bs[sr * LDT + sk] = bv0;
        *(uint4*)&Bs[sr * LDT + sk + 8] = bv1;
        __syncthreads();
        if (ks + 1 < NST) {
            const unsigned short* bp2 = W1t + (size_t)sr * KPAD + (ks + 1) * 32 + sk;
            bv0 = *(const uint4*)bp2;
            bv1 = *(const uint4*)(bp2 + 8);
        }
        bf16x8 afr[4], bfr[4];
#pragma unroll
        for (int i = 0; i < 4; i++) {
            afr[i] = *reinterpret_cast<const bf16x8*>(&As[(wr + i * 16 + fr) * LDT + kg * 8]);
            bfr[i] = *reinterpret_cast<const bf16x8*>(&Bs[(wc + i * 16 + fr) * LDT + kg * 8]);
        }
#pragma unroll
        for (int i = 0; i < 4; i++)
#pragma unroll
            for (int j = 0; j < 4; j++)
                acc[i][j] = __builtin_amdgcn_mfma_f32_16x16x32_bf16(afr[i], bfr[j], acc[i][j], 0, 0, 0);
    }
    const int rg = lane >> 4;
#pragma unroll
    for (int i = 0; i < 4; i++) {
#pragma unroll
        for (int j = 0; j < 4; j++) {
            int col = wc + j * 16 + fr;
            float sc = g[col] * rsqrtf(bv[col] + 1e-5f);
            float sh = bb[col] - bm[col] * sc;
            float bc = b1[col];
#pragma unroll
            for (int r = 0; r < 4; r++) {
                int row = nb + wr + i * 16 + rg * 4 + r;
                if (row < N) {
                    float y = (acc[i][j][r] + bc) * sc + sh;
                    y = fmaxf(y, 0.f);
                    xh[(size_t)row * KXH + 128 + col] = f2bf(y);
                }
            }
        }
    }
}

// ========= GAT per-layer node GEMM: double-buffered LDS (1 barrier/K-step) =========
// grid (4 col-tiles, nTilesM): consecutive blockIdx.x share the A tile (L2/L3 reuse).
// Fused epilogue: + cw[batch[row]] gather, bf16 C write, attention logits a_src/a_dst.
__global__ __launch_bounds__(256) void k_gemm3(const unsigned short* __restrict__ A, int M,
                                               const unsigned short* __restrict__ Bt,
                                               unsigned short* __restrict__ C,
                                               const int* __restrict__ batch,
                                               const float* __restrict__ cw,
                                               const float* __restrict__ att_s,
                                               const float* __restrict__ att_d,
                                               float* __restrict__ a_src,
                                               float* __restrict__ a_dst) {
    constexpr int LDT = 40;
    __shared__ unsigned short As[2][128 * LDT];
    __shared__ unsigned short Bs[2][128 * LDT];
    const int tid = threadIdx.x;
    const int lane = tid & 63, wid = tid >> 6;
    const int m0 = blockIdx.y * 128, n0 = blockIdx.x * 128;
    const int wr = (wid >> 1) * 64, wc = (wid & 1) * 64;
    const int sr = tid >> 1, sk = (tid & 1) * 16;
    f32x4 acc[4][4];
#pragma unroll
    for (int i = 0; i < 4; i++)
#pragma unroll
        for (int j = 0; j < 4; j++)
#pragma unroll
            for (int r = 0; r < 4; r++) acc[i][j][r] = 0.f;
    const int arow = min(m0 + sr, M - 1);
    const unsigned short* ap = A + (size_t)arow * KXH + sk;
    const unsigned short* bp = Bt + (size_t)(n0 + sr) * KXH + sk;
    uint4 av0 = *(const uint4*)ap, av1 = *(const uint4*)(ap + 8);
    uint4 bv0 = *(const uint4*)bp, bv1 = *(const uint4*)(bp + 8);
    const int fr = lane & 15, kg = lane >> 4;
    constexpr int NST = KXH / 32;  // 8
    for (int ks = 0; ks < NST; ++ks) {
        unsigned short* as = As[ks & 1];
        unsigned short* bs = Bs[ks & 1];
        *(uint4*)&as[sr * LDT + sk] = av0;
        *(uint4*)&as[sr * LDT + sk + 8] = av1;
        *(uint4*)&bs[sr * LDT + sk] = bv0;
        *(uint4*)&bs[sr * LDT + sk + 8] = bv1;
        __syncthreads();
        if (ks + 1 < NST) {  // prefetch next K-step; overlaps with MFMA below
            av0 = *(const uint4*)(ap + (ks + 1) * 32);
            av1 = *(const uint4*)(ap + (ks + 1) * 32 + 8);
            bv0 = *(const uint4*)(bp + (ks + 1) * 32);
            bv1 = *(const uint4*)(bp + (ks + 1) * 32 + 8);
        }
        bf16x8 afr[4], bfr[4];
#pragma unroll
        for (int i = 0; i < 4; i++) {
            afr[i] = *reinterpret_cast<const bf16x8*>(&as[(wr + i * 16 + fr) * LDT + kg * 8]);
            bfr[i] = *reinterpret_cast<const bf16x8*>(&bs[(wc + i * 16 + fr) * LDT + kg * 8]);
        }
#pragma unroll
        for (int i = 0; i < 4; i++)
#pragma unroll
            for (int j = 0; j < 4; j++)
                acc[i][j] = __builtin_amdgcn_mfma_f32_16x16x32_bf16(afr[i], bfr[j], acc[i][j], 0, 0, 0);
    }
    const int rg = lane >> 4;  // C/D: col = lane&15, row = (lane>>4)*4 + reg
    float pssum[4][4], pdsum[4][4];
#pragma unroll
    for (int i = 0; i < 4; i++)
#pragma unroll
        for (int r = 0; r < 4; r++) { pssum[i][r] = 0.f; pdsum[i][r] = 0.f; }
#pragma unroll
    for (int i = 0; i < 4; i++) {
#pragma unroll
        for (int j = 0; j < 4; j++) {
            int col = n0 + wc + j * 16 + fr;
            float asw = att_s[col], adw = att_d[col];
#pragma unroll
            for (int r = 0; r < 4; r++) {
                int row = m0 + wr + i * 16 + rg * 4 + r;
                if (row < M) {
                    float vv = acc[i][j][r] + cw[(size_t)batch[row] * 512 + col];
                    C[(size_t)row * 512 + col] = f2bf(vv);
                    pssum[i][r] += vv * asw;
                    pdsum[i][r] += vv * adw;
                }
            }
        }
    }
    __syncthreads();  // LDS is dead; reuse for cross-wave att combine
    float* lat = (float*)&As[0][0];  // [4 waves][64 rows][2]
#pragma unroll
    for (int i = 0; i < 4; i++) {
#pragma unroll
        for (int r = 0; r < 4; r++) {
            float s = pssum[i][r], d = pdsum[i][r];
#pragma unroll
            for (int dd = 1; dd < 16; dd <<= 1) {
                s += __shfl_xor(s, dd);
                d += __shfl_xor(d, dd);
            }
            if (fr == 0) {
                int k = i * 16 + rg * 4 + r;
                lat[(wid * 64 + k) * 2] = s;
                lat[(wid * 64 + k) * 2 + 1] = d;
            }
        }
    }
    __syncthreads();
    if ((wid & 1) == 0) {
        int k = lane;
        int row = m0 + (wid >> 1) * 64 + k;
        if (row < M) {
            float s = lat[(wid * 64 + k) * 2] + lat[((wid + 1) * 64 + k) * 2];
            float d = lat[(wid * 64 + k) * 2 + 1] + lat[((wid + 1) * 64 + k) * 2 + 1];
            int head = n0 >> 7;
            a_src[(size_t)row * 4 + head] = s;
            a_dst[(size_t)row * 4 + head] = d;
        }
    }
}

// ---------------- CSR build ----------------
__global__ void k_cnt(const int* __restrict__ ei, int E, int* cnt) {
    int i = blockIdx.x * 256 + threadIdx.x;
    if (i < E) atomicAdd(&cnt[ei[E + i]], 1);
}
__global__ __launch_bounds__(1024) void k_scan(const int* __restrict__ cnt, int* __restrict__ rowptr,
                                               int* __restrict__ cursor, int n) {
    __shared__ int wsum[16];
    __shared__ int carry;
    int tid = threadIdx.x, lane = tid & 63, wid = tid >> 6;
    if (tid == 0) carry = 0;
    __syncthreads();
    for (int basei = 0; basei < n; basei += 1024) {
        int i = basei + tid;
        int v = (i < n) ? cnt[i] : 0;
        int s = v;
#pragma unroll
        for (int d = 1; d < 64; d <<= 1) {
            int t = __shfl_up(s, (unsigned)d);
            if (lane >= d) s += t;
        }
        if (lane == 63) wsum[wid] = s;
        __syncthreads();
        if (wid == 0 && lane < 16) {
            int ws = wsum[lane]; int t = ws;
#pragma unroll
            for (int d = 1; d < 16; d <<= 1) {
                int u = __shfl_up(t, (unsigned)d);
                if (lane >= d) t += u;
            }
            wsum[lane] = t - ws;  // exclusive wave offsets
        }
        __syncthreads();
        int excl = carry + wsum[wid] + (s - v);
        if (i < n) { rowptr[i] = excl; cursor[i] = excl; }
        __syncthreads();
        if (tid == 1023) carry += wsum[15] + s;
        __syncthreads();
    }
    if (tid == 0) rowptr[n] = carry;
}
__global__ void k_fill(const int* __restrict__ ei, int E, int N, int* cursor, int* csrc) {
    int i = blockIdx.x * 256 + threadIdx.x;
    if (i >= E + N) return;
    int s, d;
    if (i < E) { s = ei[i]; d = ei[E + i]; }
    else { s = i - E; d = s; }
    int slot = atomicAdd(&cursor[d], 1);
    csrc[slot] = s;
}

// ---------------- GAT aggregation: one-pass softmax + LDS-staged 2-deep gather ----------------
__global__ __launch_bounds__(256) void k_agg(const int* __restrict__ rowptr,
                                             const int* __restrict__ csrc,
                                             const float* __restrict__ asrc,
                                             const float* __restrict__ adstv,
                                             const unsigned short* __restrict__ xs,
                                             const float* __restrict__ gbias,
                                             const float* __restrict__ bg,
                                             const float* __restrict__ bb,
                                             const float* __restrict__ bm,
                                             const float* __restrict__ bv,
                                             float* __restrict__ x,
                                             unsigned short* __restrict__ xh, int N) {
    __shared__ float wsh[4][64][4];
    __shared__ int ssh[4][64];
    int tid = threadIdx.x, lane = tid & 63, wid = tid >> 6;
    int n = blockIdx.x * 4 + wid;
    if (n >= N) return;
    int beg = rowptr[n], end = rowptr[n + 1];
    float4 ad = *(const float4*)(adstv + (size_t)n * 4);
    int nch = (end - beg + 63) >> 6;
    // phase A: online per-head max & denom (lane i owns edge beg+i of each chunk)
    float m0 = -1e30f, m1 = -1e30f, m2 = -1e30f, m3 = -1e30f;
    float s0 = 0.f, s1 = 0.f, s2 = 0.f, s3 = 0.f;
    float a0 = -1e30f, a1 = -1e30f, a2 = -1e30f, a3 = -1e30f;  // persisted (single-chunk reuse)
    int sv = 0;
    for (int base = beg; base < end; base += 64) {
        int idx = base + lane;
        float b0 = -1e30f, b1 = -1e30f, b2 = -1e30f, b3 = -1e30f;
        int s = 0;
        if (idx < end) {
            s = csrc[idx];
            float4 t = *(const float4*)(asrc + (size_t)s * 4);
            b0 = t.x + ad.x; b0 = b0 > 0.f ? b0 : 0.2f * b0;
            b1 = t.y + ad.y; b1 = b1 > 0.f ? b1 : 0.2f * b1;
            b2 = t.z + ad.z; b2 = b2 > 0.f ? b2 : 0.2f * b2;
            b3 = t.w + ad.w; b3 = b3 > 0.f ? b3 : 0.2f * b3;
        }
        float c0 = b0, c1 = b1, c2 = b2, c3 = b3;
#pragma unroll
        for (int d = 1; d < 64; d <<= 1) {
            c0 = fmaxf(c0, __shfl_xor(c0, d));
            c1 = fmaxf(c1, __shfl_xor(c1, d));
            c2 = fmaxf(c2, __shfl_xor(c2, d));
            c3 = fmaxf(c3, __shfl_xor(c3, d));
        }
        float nm0 = fmaxf(m0, c0), nm1 = fmaxf(m1, c1), nm2 = fmaxf(m2, c2), nm3 = fmaxf(m3, c3);
        float e0 = (idx < end) ? __expf(b0 - nm0) : 0.f;
        float e1 = (idx < end) ? __expf(b1 - nm1) : 0.f;
        float e2 = (idx < end) ? __expf(b2 - nm2) : 0.f;
        float e3 = (idx < end) ? __expf(b3 - nm3) : 0.f;
#pragma unroll
        for (int d = 1; d < 64; d <<= 1) {
            e0 += __shfl_xor(e0, d); e1 += __shfl_xor(e1, d);
            e2 += __shfl_xor(e2, d); e3 += __shfl_xor(e3, d);
        }
        s0 = s0 * __expf(m0 - nm0) + e0; m0 = nm0;
        s1 = s1 * __expf(m1 - nm1) + e1; m1 = nm1;
        s2 = s2 * __expf(m2 - nm2) + e2; m2 = nm2;
        s3 = s3 * __expf(m3 - nm3) + e3; m3 = nm3;
        a0 = b0; a1 = b1; a2 = b2; a3 = b3; sv = s;
    }
    float i0 = 1.f / fmaxf(s0, 1e-16f), i1 = 1.f / fmaxf(s1, 1e-16f);
    float i2 = 1.f / fmaxf(s2, 1e-16f), i3 = 1.f / fmaxf(s3, 1e-16f);
    // phase B: weighted gather, per-edge weights staged in LDS (wave-private), 2-deep
    const int h = lane >> 4, c0i = (lane & 15) * 8;
    float acc[8];
#pragma unroll
    for (int j = 0; j < 8; j++) acc[j] = 0.f;
    for (int base = beg; base < end; base += 64) {
        int s; float w0, w1, w2, w3;
        if (nch == 1) {
            s = sv;
            w0 = __expf(a0 - m0) * i0; w1 = __expf(a1 - m1) * i1;
            w2 = __expf(a2 - m2) * i2; w3 = __expf(a3 - m3) * i3;
        } else {
            int idx = base + lane;
            float b0 = -1e30f, b1 = -1e30f, b2 = -1e30f, b3 = -1e30f;
            s = 0;
            if (idx < end) {
                s = csrc[idx];
                float4 t = *(const float4*)(asrc + (size_t)s * 4);
                b0 = t.x + ad.x; b0 = b0 > 0.f ? b0 : 0.2f * b0;
                b1 = t.y + ad.y; b1 = b1 > 0.f ? b1 : 0.2f * b1;
                b2 = t.z + ad.z; b2 = b2 > 0.f ? b2 : 0.2f * b2;
                b3 = t.w + ad.w; b3 = b3 > 0.f ? b3 : 0.2f * b3;
            }
            w0 = __expf(b0 - m0) * i0; w1 = __expf(b1 - m1) * i1;
            w2 = __expf(b2 - m2) * i2; w3 = __expf(b3 - m3) * i3;
        }
        ssh[wid][lane] = s;
        wsh[wid][lane][0] = w0; wsh[wid][lane][1] = w1;
        wsh[wid][lane][2] = w2; wsh[wid][lane][3] = w3;
        int cnt = min(64, end - base);
        int i = 0;
        for (; i + 2 <= cnt; i += 2) {
            int sa = ssh[wid][i], sb = ssh[wid][i + 1];
            float wa = wsh[wid][i][h], wb = wsh[wid][i + 1][h];
            uint4 ra = *(const uint4*)(xs + ((size_t)sa << 9) + (h << 7) + c0i);
            uint4 rb = *(const uint4*)(xs + ((size_t)sb << 9) + (h << 7) + c0i);
            const unsigned short* qa = (const unsigned short*)&ra;
            const unsigned short* qb = (const unsigned short*)&rb;
#pragma unroll
            for (int j = 0; j < 8; j++) acc[j] += wa * bf2f(qa[j]);
#pragma unroll
            for (int j = 0; j < 8; j++) acc[j] += wb * bf2f(qb[j]);
        }
        if (i < cnt) {
            int sa = ssh[wid][i];
            float wa = wsh[wid][i][h];
            uint4 ra = *(const uint4*)(xs + ((size_t)sa << 9) + (h << 7) + c0i);
            const unsigned short* qa = (const unsigned short*)&ra;
#pragma unroll
            for (int j = 0; j < 8; j++) acc[j] += wa * bf2f(qa[j]);
        }
    }
    // head mean across lanes (h = lane>>4)
#pragma unroll
    for (int j = 0; j < 8; j++) {
        acc[j] += __shfl_xor(acc[j], 16);
        acc[j] += __shfl_xor(acc[j], 32);
    }
    if (lane < 16) {
#pragma unroll
        for (int j = 0; j < 8; j++) {
            int c = c0i + j;
            float t = acc[j] * 0.25f + gbias[c];
            float sc = bg[c] * rsqrtf(bv[c] + 1e-5f);
            float y = (t - bm[c]) * sc + bb[c];
            float ge = 0.5f * y * (1.f + erff(y * 0.70710678118f));
            float xn = x[(size_t)n * 128 + c] + ge;
            x[(size_t)n * 128 + c] = xn;
            xh[(size_t)n * KXH + c] = f2bf(xn);
        }
    }
}

// ---------------- fused pool + final linear ----------------
__global__ __launch_bounds__(256) void k_pool(const float* __restrict__ x,
                                              const int* __restrict__ batch,
                                              const float* __restrict__ W,
                                              const float* __restrict__ bo,
                                              float* __restrict__ out, int N) {
    __shared__ float xg[128];
    __shared__ float tmp[256];
    __shared__ int bounds[2];
    int g = blockIdx.x, tid = threadIdx.x;
    if (tid < 2) {
        int key = g + tid, lo = 0, hi = N;
        while (lo < hi) { int mid = (lo + hi) >> 1; if (batch[mid] < key) lo = mid + 1; else hi = mid; }
        bounds[tid] = lo;
    }
    __syncthreads();
    int s = bounds[0], e = bounds[1];
    int c = tid & 127, rgp = tid >> 7;
    float a = 0.f;
    for (int n = s + rgp; n < e; n += 2) a += x[(size_t)n * 128 + c];
    tmp[tid] = a;
    __syncthreads();
    if (tid < 128) xg[tid] = tmp[tid] + tmp[tid + 128];
    __syncthreads();
    float cntf = (float)(e - s);
    for (int j = tid; j < 1024; j += 256) {
        float o = cntf * bo[j];
        for (int cc = 0; cc < 128; cc++) o += xg[cc] * W[(size_t)cc * 1024 + j];
        out[(size_t)g * 1024 + j] = o;
    }
}

extern "C" void kernel_launch(void* const* d_in, const int* in_sizes, int n_in,
                              void* d_out, int out_size, void* d_ws, size_t ws_size,
                              hipStream_t stream) {
    const int N = in_sizes[0];
    const int E = in_sizes[2] / 2;
    const int NG = in_sizes[5] / CTXD;
    const int* at = (const int*)d_in[0];
    const float* pos = (const float*)d_in[1];
    const int* ei = (const int*)d_in[2];
    const int* batch = (const int*)d_in[4];
    const float* ctx = (const float*)d_in[5];
    const float* embW = (const float*)d_in[6];
    const float* embB = (const float*)d_in[7];
    const float* W1 = (const float*)d_in[8];
    const float* b1 = (const float*)d_in[9];
    const float* rg = (const float*)d_in[10];
    const float* rb = (const float*)d_in[11];
    const float* rm = (const float*)d_in[12];
    const float* rv = (const float*)d_in[13];
    const float* W2 = (const float*)d_in[14];
    const float* b2 = (const float*)d_in[15];
    const float* gatW = (const float*)d_in[16];
    const float* atts = (const float*)d_in[17];
    const float* attd = (const float*)d_in[18];
    const float* gbias = (const float*)d_in[19];
    const float* bg = (const float*)d_in[20];
    const float* bbb = (const float*)d_in[21];
    const float* bm = (const float*)d_in[22];
    const float* bv = (const float*)d_in[23];
    const float* outW = (const float*)d_in[24];
    const float* outb = (const float*)d_in[25];
    float* out = (float*)d_out;

    char* basep = (char*)d_ws;
    size_t off = 0;
    auto alloc = [&](size_t bytes) -> char* {
        char* p = basep + off;
        off = (off + bytes + 255) & ~(size_t)255;
        return p;
    };
    unsigned short* xh = (unsigned short*)alloc((size_t)N * KXH * 2);
    float* x = (float*)alloc((size_t)N * 128 * 4);
    unsigned short* xs = (unsigned short*)alloc((size_t)N * 512 * 2);
    float* a_src = (float*)alloc((size_t)N * 4 * 4);
    float* a_dst = (float*)alloc((size_t)N * 4 * 4);
    int* cnt = (int*)alloc((size_t)N * 4);
    int* rowptr = (int*)alloc((size_t)(N + 1) * 4);
    int* cursor = (int*)alloc((size_t)N * 4);
    int* csrc = (int*)alloc((size_t)(E + N) * 4);
    unsigned short* gatWt = (unsigned short*)alloc((size_t)NLAYERS * 512 * 2176 * 2);
    unsigned short* W1t = (unsigned short*)alloc((size_t)128 * KPAD * 2);
    unsigned short* W2bf = (unsigned short*)alloc((size_t)128 * CTXD * 2);
    unsigned short* cpre = (unsigned short*)alloc((size_t)NG * CTXD * 2);
    unsigned short* Bc = (unsigned short*)alloc((size_t)NLAYERS * 512 * KXH * 2);
    float* cW = (float*)alloc((size_t)NLAYERS * NG * 512 * 4);
    (void)ws_size; (void)n_in; (void)out_size;

    // ---- merged input-only prep ----
    {
        int nbW1t = (128 * KPAD + 255) / 256;
        int nbW2 = (128 * CTXD + 255) / 256;
        int nbCp = (NG * CTXD + 255) / 256;
        int nbCi = (N + 255) / 256;
        int nbEm = (N * 128 + 255) / 256;
        int nbTr = 16 * 68 * 3;
        int e0 = nbW1t, e1 = e0 + nbW2, e2 = e1 + nbCp, e3 = e2 + nbCi, e4 = e3 + nbEm;
        int total = e4 + nbTr;
        k_misc<<<total, 256, 0, stream>>>(W1, W1t, W2, W2bf, ctx, b2, cpre, cnt,
                                          at, embW, embB, x, xh, gatW, gatWt,
                                          N, NG, e0, e1, e2, e3, e4);
    }
    k_cnt<<<(E + 255) / 256, 256, 0, stream>>>(ei, E, cnt);
    // ---- merged RBF + weight-prep GEMMs + Bc copy ----
    {
        int nbRbf = (N + 127) / 128;
        int nbBc = (NLAYERS * 512 * 128 + 255) / 256;
        k_rbfprep<<<nbRbf + 24 + nbBc, 256, 0, stream>>>(pos, W1t, b1, rg, rb, rm, rv, xh,
                                                         gatWt, W2bf, cpre, Bc, cW, N, NG, nbRbf);
    }
    k_scan<<<1, 1024, 0, stream>>>(cnt, rowptr, cursor, N);
    k_fill<<<(E + N + 255) / 256, 256, 0, stream>>>(ei, E, N, cursor, csrc);
    // ---- GAT layers ----
    {
        dim3 g(4, (N + 127) / 128, 1);  // x = col-tile (head): adjacent blocks share A tile
        for (int l = 0; l < NLAYERS; l++) {
            k_gemm3<<<g, 256, 0, stream>>>(xh, N, Bc + (size_t)l * 512 * KXH,
                                           xs, batch, cW + (size_t)l * NG * 512,
                                           atts + l * 512, attd + l * 512, a_src, a_dst);
            k_agg<<<(N + 3) / 4, 256, 0, stream>>>(rowptr, csrc, a_src, a_dst, xs,
                                                   gbias + l * 128, bg + l * 128, bbb + l * 128,
                                                   bm + l * 128, bv + l * 128, x, xh, N);
        }
    }
    k_pool<<<NG, 256, 0, stream>>>(x, batch, outW, outb, out, N);
}